// Round 8
// baseline (11179.047 us; speedup 1.0000x reference)
//
#include <hip/hip_runtime.h>
#include <hip/hip_bf16.h>
#include <float.h>

typedef __hip_bfloat16 bf16;

#define NEG_BIG (-1.0e30f)

__device__ __forceinline__ bf16 f2b(float v){ return __float2bfloat16(v); }
__device__ __forceinline__ float lrelu(float x){ return x >= 0.f ? x : 0.2f*x; }

// dtype-flexible sanitized load from a raw INPUT buffer (element index)
__device__ __forceinline__ float ldx(const void* p, size_t i, int isbf){
  float v = isbf ? __bfloat162float(((const bf16*)p)[i]) : ((const float*)p)[i];
  return (v == v && fabsf(v) < 1e30f) ? v : 0.f;
}
// dtype-flexible store to the OUTPUT buffer (element index)
__device__ __forceinline__ void stout(void* p, size_t i, float v, int isbf){
  if (isbf) ((bf16*)p)[i] = f2b(v);
  else      ((float*)p)[i] = v;
}

// ---------------- input dtype detector ----------------
__global__ void detect_kernel(const unsigned int* __restrict__ X, int* __restrict__ flag){
  __shared__ int cnt;
  if (threadIdx.x == 0) cnt = 0;
  __syncthreads();
  int hits = 0;
  for (int i = threadIdx.x; i < 8192; i += 256){
    unsigned w = X[i];
    unsigned lo = w & 0xFFFFu;
    unsigned e = (lo >> 7) & 0xFFu;
    if ((e >= 0x76u && e <= 0x84u) || lo == 0u) hits++;
  }
  atomicAdd(&cnt, hits);
  __syncthreads();
  if (threadIdx.x == 0) flag[0] = (cnt > 4096) ? 1 : 0;
}

// ---------------- weight prep ----------------
__global__ void wt_kernel(const void* __restrict__ W, const int* __restrict__ dtf,
                          int Cout, int pitch, int coff, int Cin, float* __restrict__ WT){
  int i = blockIdx.x*256 + threadIdx.x;
  if (i >= Cin*Cout) return;
  int isbf = *dtf;
  int c = i / Cout, o = i - c*Cout;
  WT[i] = ldx(W, (size_t)o*pitch + coff + c, isbf);
}

__global__ void w0_kernel(const void* __restrict__ W0, const int* __restrict__ dtf,
                          int C, float* __restrict__ WaT, float* __restrict__ WqT){
  int i = blockIdx.x*256 + threadIdx.x;
  if (i >= C*64) return;
  int isbf = *dtf;
  int c = i >> 6, o = i & 63;
  float a = ldx(W0, (size_t)o*2*C + c, isbf);
  float q = ldx(W0, (size_t)o*2*C + C + c, isbf);
  WaT[i] = a; WqT[i] = q - a;
}

__global__ void xconv_kernel(const void* __restrict__ x, const int* __restrict__ dtf,
                             float* __restrict__ xfT){
  int i = blockIdx.x*256 + threadIdx.x;
  if (i >= 4*4096) return;
  int isbf = *dtf;
  int b = i >> 12, n = i & 4095;
  for (int c = 0; c < 9; c++)
    xfT[((size_t)b*4096 + n)*9 + c] = ldx(x, ((size_t)b*9 + c)*4096 + n, isbf);
}

__global__ void nodecopy_kernel(const void* __restrict__ x, const int* __restrict__ dtf,
                                void* __restrict__ out){
  int i = blockIdx.x*256 + threadIdx.x;
  int isbf = *dtf;
  if (i < 12288){
    int b = i / 3072, r = i % 3072; int c = r / 1024, m = r % 1024;
    stout(out, 212992 + i, ldx(x, ((size_t)b*9 + c)*4096 + m, isbf), isbf);
  } else if (i < 15360){
    int j = i - 12288; int b = j / 768, r = j % 768; int c = r / 256, m = r % 256;
    stout(out, 212992 + i, ldx(x, ((size_t)b*9 + c)*4096 + m, isbf), isbf);
  } else if (i < 16128){
    int j = i - 15360; int b = j / 192, r = j % 192; int c = r / 64, m = r % 64;
    stout(out, 212992 + i, ldx(x, ((size_t)b*9 + c)*4096 + m, isbf), isbf);
  }
}

// ---------------- kNN ----------------
__global__ void rownorm_kernel(const float* __restrict__ T, int pitch, size_t bs,
                               int C, int N, float* __restrict__ rr){
  int n = blockIdx.x*256 + threadIdx.x;
  int b = blockIdx.y;
  if (n >= N) return;
  const float* row = T + (size_t)b*bs + (size_t)n*pitch;
  float s = 0.f;
  for (int c = 0; c < C; c++) s = fmaf(row[c], row[c], s);
  rr[b*N + n] = s;
}

// small-C chunked kNN (C=3/9; per-thread query in registers, refs staged in LDS)
template<int C, int K, int TN>
__global__ void knn_chunk_kernel(const float* __restrict__ qT, int qpitch, size_t qbs,
                                 const float* __restrict__ rT, int rpitch, size_t rbs,
                                 const float* __restrict__ rr, int M, int N, int NC,
                                 float* __restrict__ cval, int* __restrict__ cidx){
  __shared__ float sR[TN*C];
  __shared__ float sN[TN];
  int tid = threadIdx.x;
  int m = blockIdx.x*256 + tid;
  int cid = blockIdx.y, b = blockIdx.z;
  int len = N / NC;
  int n0 = cid * len;
  bool active = (m < M);
  float q[C]; float qq = 0.f;
  if (active){
    const float* qrow = qT + (size_t)b*qbs + (size_t)m*qpitch;
    #pragma unroll
    for (int c = 0; c < C; c++){ q[c] = qrow[c]; qq = fmaf(q[c], q[c], qq); }
  }
  float bv[K]; int bi[K];
  #pragma unroll
  for (int j = 0; j < K; j++){ bv[j] = NEG_BIG; bi[j] = n0; }
  float minv = NEG_BIG; int minpos = 0;
  auto ins = [&](float d, int j){
    if (d > minv){
      #pragma unroll
      for (int s = 0; s < K; s++) if (s == minpos){ bv[s] = d; bi[s] = j; }
      minv = bv[0]; minpos = 0;
      #pragma unroll
      for (int s = 1; s < K; s++) if (bv[s] < minv){ minv = bv[s]; minpos = s; }
    }
  };
  const float* rbase = rT + (size_t)b*rbs;
  const float* rrb = rr + b*N;
  for (int t0 = 0; t0 < len; t0 += TN){
    __syncthreads();
    for (int i = tid; i < TN*C; i += 256){
      int t = i / C, c = i - t*C;
      sR[i] = rbase[(size_t)(n0 + t0 + t)*rpitch + c];
    }
    for (int i = tid; i < TN; i += 256) sN[i] = rrb[n0 + t0 + i];
    __syncthreads();
    if (active){
      for (int t = 0; t < TN; t += 4){
        float a0 = 0.f, a1 = 0.f, a2 = 0.f, a3 = 0.f;
        #pragma unroll
        for (int c = 0; c < C; c++){
          float qc = q[c];
          a0 = fmaf(qc, sR[(t+0)*C + c], a0);
          a1 = fmaf(qc, sR[(t+1)*C + c], a1);
          a2 = fmaf(qc, sR[(t+2)*C + c], a2);
          a3 = fmaf(qc, sR[(t+3)*C + c], a3);
        }
        int jb = n0 + t0 + t;
        ins(2.f*a0 - qq - sN[t+0], jb+0);
        ins(2.f*a1 - qq - sN[t+1], jb+1);
        ins(2.f*a2 - qq - sN[t+2], jb+2);
        ins(2.f*a3 - qq - sN[t+3], jb+3);
      }
    }
  }
  if (active){
    float* ov = cval + ((size_t)((size_t)b*M + m)*NC + cid)*K;
    int*   oi = cidx + ((size_t)((size_t)b*M + m)*NC + cid)*K;
    #pragma unroll
    for (int j = 0; j < K; j++){ ov[j] = bv[j]; oi[j] = bi[j]; }
  }
}

// C=64 self-kNN, ref-split: block = 4 waves × 64 shared queries (LDS, pad 65);
// wave w scans len/4 refs of chunk cid (R6's proven scan loop, unchanged);
// post-scan LDS dump + wave-0 rescan merge (fresh arrays -> no spill).
template<int K>
__global__ void knn_split64_kernel(const float* __restrict__ fT, const float* __restrict__ rr,
                                   int N, int NC, float* __restrict__ cval, int* __restrict__ cidx){
  constexpr int MRG = 4*64*K;
  constexpr int HEAD = (MRG > 64*65) ? MRG : 64*65;
  __shared__ float smem[HEAD + MRG];
  float* sMv = smem;
  int*   sMi = (int*)(smem + HEAD);
  int tid = threadIdx.x;
  int w = tid >> 6, lane = tid & 63;
  int q0 = blockIdx.x*64;
  int cid = blockIdx.y, b = blockIdx.z;
  int m = q0 + lane;
  int len = N / NC;
  int len4 = len >> 2;
  int n0 = cid*len + w*len4;
  // stage 64 queries (pad 65 -> conflict-free per-lane reads)
  for (int i = tid; i < 64*64; i += 256){
    int qi = i >> 6, c = i & 63;
    smem[qi*65 + c] = fT[((size_t)b*N + q0 + qi)*64 + c];
  }
  __syncthreads();
  float qq = rr[(size_t)b*N + m];    // self-kNN
  float bv[K]; int bi[K];
  #pragma unroll
  for (int j = 0; j < K; j++){ bv[j] = NEG_BIG; bi[j] = n0; }
  float minv = NEG_BIG; int minpos = 0;
  auto ins = [&](float d, int j){
    if (d > minv){
      #pragma unroll
      for (int s = 0; s < K; s++) if (s == minpos){ bv[s] = d; bi[s] = j; }
      minv = bv[0]; minpos = 0;
      #pragma unroll
      for (int s = 1; s < K; s++) if (bv[s] < minv){ minv = bv[s]; minpos = s; }
    }
  };
  {
    const float4* rbase = (const float4*)(fT + ((size_t)b*N + n0)*64);
    const float* rrb = rr + (size_t)b*N + n0;
    const float* qrow = smem + lane*65;
    for (int t0 = 0; t0 < len4; t0 += 4){
      const float4* r4 = rbase + (size_t)t0*16;
      float a0=0.f, a1=0.f, a2=0.f, a3=0.f;
      #pragma unroll
      for (int ct = 0; ct < 16; ct++){
        float4 v0 = r4[ct], v1 = r4[16+ct], v2 = r4[32+ct], v3 = r4[48+ct];
        float qa = qrow[ct*4+0], qb = qrow[ct*4+1], qc = qrow[ct*4+2], qd = qrow[ct*4+3];
        a0 = fmaf(qa,v0.x,a0); a0 = fmaf(qb,v0.y,a0); a0 = fmaf(qc,v0.z,a0); a0 = fmaf(qd,v0.w,a0);
        a1 = fmaf(qa,v1.x,a1); a1 = fmaf(qb,v1.y,a1); a1 = fmaf(qc,v1.z,a1); a1 = fmaf(qd,v1.w,a1);
        a2 = fmaf(qa,v2.x,a2); a2 = fmaf(qb,v2.y,a2); a2 = fmaf(qc,v2.z,a2); a2 = fmaf(qd,v2.w,a2);
        a3 = fmaf(qa,v3.x,a3); a3 = fmaf(qb,v3.y,a3); a3 = fmaf(qc,v3.z,a3); a3 = fmaf(qd,v3.w,a3);
      }
      ins(2.f*a0 - qq - rrb[t0+0], n0+t0+0);
      ins(2.f*a1 - qq - rrb[t0+1], n0+t0+1);
      ins(2.f*a2 - qq - rrb[t0+2], n0+t0+2);
      ins(2.f*a3 - qq - rrb[t0+3], n0+t0+3);
    }
  }
  // all scans done; query region no longer needed -> dump per-wave top-K
  __syncthreads();
  #pragma unroll
  for (int j = 0; j < K; j++){
    sMv[tid*K + j] = bv[j];
    sMi[tid*K + j] = bi[j];
  }
  __syncthreads();
  if (w == 0){
    float mv[K]; int mi[K];
    #pragma unroll
    for (int j = 0; j < K; j++){ mv[j] = NEG_BIG; mi[j] = n0; }
    float minv2 = NEG_BIG; int minpos2 = 0;
    for (int ww = 0; ww < 4; ww++){
      #pragma unroll
      for (int j = 0; j < K; j++){
        float d = sMv[(ww*64 + lane)*K + j];
        int jj = sMi[(ww*64 + lane)*K + j];
        if (d > minv2){
          #pragma unroll
          for (int s = 0; s < K; s++) if (s == minpos2){ mv[s] = d; mi[s] = jj; }
          minv2 = mv[0]; minpos2 = 0;
          #pragma unroll
          for (int s = 1; s < K; s++) if (mv[s] < minv2){ minv2 = mv[s]; minpos2 = s; }
        }
      }
    }
    float* ov = cval + ((size_t)((size_t)b*N + m)*NC + cid)*K;
    int*   oi = cidx + ((size_t)((size_t)b*N + m)*NC + cid)*K;
    #pragma unroll
    for (int j = 0; j < K; j++){ ov[j] = mv[j]; oi[j] = mi[j]; }
  }
}

template<int K>
__global__ void knn_merge_kernel(const float* __restrict__ cval, const int* __restrict__ cidx,
                                 int M, int NC, int* __restrict__ idxo){
  int i = blockIdx.x*256 + threadIdx.x;   // b*M + m
  if (i >= 4*M) return;
  const float* cv = cval + (size_t)i*NC*K;
  const int*   ci = cidx + (size_t)i*NC*K;
  float bv[K]; int bi[K];
  #pragma unroll
  for (int j = 0; j < K; j++){ bv[j] = NEG_BIG; bi[j] = 0; }
  float minv = NEG_BIG; int minpos = 0;
  int T = NC*K;
  for (int t = 0; t < T; t++){
    float d = cv[t];
    if (d > minv){
      int j = ci[t];
      #pragma unroll
      for (int s = 0; s < K; s++) if (s == minpos){ bv[s] = d; bi[s] = j; }
      minv = bv[0]; minpos = 0;
      #pragma unroll
      for (int s = 1; s < K; s++) if (bv[s] < minv){ minv = bv[s]; minpos = s; }
    }
  }
  int* orow = idxo + (size_t)i*K;
  #pragma unroll
  for (int j = 0; j < K; j++) orow[j] = bi[j];
}

// ---------------- edge conv ----------------
__global__ void pq_kernel(const float* __restrict__ xT, int pitch, int C,
                          const float* __restrict__ WaT,
                          float* __restrict__ P, int N){
  int o = threadIdx.x & 63;
  int n = blockIdx.x*4 + (threadIdx.x >> 6);
  int b = blockIdx.y;
  if (n >= N) return;
  const float* row = xT + ((size_t)b*N + n)*pitch;
  float ap = 0.f;
  for (int c = 0; c < C; c++) ap = fmaf(WaT[c*64 + o], row[c], ap);
  P[((size_t)b*N + n)*64 + o] = ap;
}

__global__ void edge2_kernel(const float* __restrict__ P, const float* __restrict__ featT,
                             int pitch, int C, const float* __restrict__ WqT,
                             const int* __restrict__ idx, const float* __restrict__ W1T,
                             float* __restrict__ outT, int N, int mask){
  __shared__ float sW[64*64];
  __shared__ float sH[20*64];
  __shared__ float sx[64];
  int o = threadIdx.x; int n = blockIdx.x; int b = blockIdx.y;
  const float4* w4 = (const float4*)W1T;
  float4* s4 = (float4*)sW;
  #pragma unroll
  for (int i = 0; i < 16; i++) s4[i*64 + o] = w4[i*64 + o];
  if (o < C) sx[o] = featT[((size_t)b*N + n)*pitch + o];
  __syncthreads();
  float qv = 0.f;
  for (int c = 0; c < C; c++) qv = fmaf(WqT[c*64 + o], sx[c], qv);
  const float* Pb = P + (size_t)b*N*64;
  const int* irow = idx + ((size_t)b*N + n)*20;
  for (int kk = 0; kk < 20; kk++){
    int j = irow[kk] & mask;
    float h = Pb[(size_t)j*64 + o] + qv;
    sH[kk*64 + o] = h >= 0.f ? h : 0.2f*h;
  }
  __syncthreads();
  float acc[20];
  #pragma unroll
  for (int kk = 0; kk < 20; kk++) acc[kk] = 0.f;
  for (int c = 0; c < 64; c += 4){
    float w0 = sW[c*64+o], w1 = sW[(c+1)*64+o], w2 = sW[(c+2)*64+o], w3 = sW[(c+3)*64+o];
    #pragma unroll
    for (int kk = 0; kk < 20; kk++){
      float4 h4 = *(const float4*)&sH[kk*64 + c];
      float a = acc[kk];
      a = fmaf(w0, h4.x, a); a = fmaf(w1, h4.y, a);
      a = fmaf(w2, h4.z, a); a = fmaf(w3, h4.w, a);
      acc[kk] = a;
    }
  }
  float m = NEG_BIG;
  #pragma unroll
  for (int kk = 0; kk < 20; kk++) m = fmaxf(m, acc[kk]);
  outT[((size_t)b*N + n)*64 + o] = lrelu(m);
}

__global__ void edge1_kernel(const float* __restrict__ P, const float* __restrict__ featT,
                             int pitch, int C, const float* __restrict__ WqT,
                             const int* __restrict__ idx, float* __restrict__ outT,
                             int N, int K, int mask){
  __shared__ float sx[64];
  int o = threadIdx.x; int n = blockIdx.x; int b = blockIdx.y;
  if (o < C) sx[o] = featT[((size_t)b*N + n)*pitch + o];
  __syncthreads();
  float qv = 0.f;
  for (int c = 0; c < C; c++) qv = fmaf(WqT[c*64 + o], sx[c], qv);
  const float* Pb = P + (size_t)b*N*64;
  const int* irow = idx + ((size_t)b*N + n)*K;
  float m = NEG_BIG;
  for (int kk = 0; kk < K; kk++){
    int j = irow[kk] & mask;
    m = fmaxf(m, Pb[(size_t)j*64 + o] + qv);
  }
  outT[((size_t)b*N + n)*64 + o] = lrelu(m);
}

__global__ void gmax_kernel(const float* __restrict__ inT, const int* __restrict__ idx,
                            float* __restrict__ outT, int Nin, int M, int K, int mask){
  int o = threadIdx.x; int m = blockIdx.x; int b = blockIdx.y;
  const float* ib = inT + (size_t)b*Nin*64;
  const int* irow = idx + ((size_t)b*M + m)*K;
  float v = NEG_BIG;
  for (int kk = 0; kk < K; kk++){
    int j = irow[kk] & mask;
    v = fmaxf(v, ib[(size_t)j*64 + o]);
  }
  outT[((size_t)b*M + m)*64 + o] = v;
}

__global__ void reluadd_kernel(float* __restrict__ x, const float* __restrict__ f, int total){
  int i = blockIdx.x*256 + threadIdx.x;
  if (i >= total) return;
  float v = x[i] + f[i];
  x[i] = v > 0.f ? v : 0.f;
}

// ---------------- global feature path ----------------
__global__ void pool_kernel(const float* __restrict__ xT, const void* __restrict__ W,
                            const int* __restrict__ dtf, float* __restrict__ partial,
                            int N, int npts, int segbase){
  __shared__ float sW[64*256];
  __shared__ float sX[32*64];
  int tid = threadIdx.x;
  int ot = blockIdx.x, chunk = blockIdx.y, b = blockIdx.z;
  int isbf = *dtf;
  for (int i = tid; i < 64*256; i += 256){
    int c = i >> 8, t = i & 255;
    sW[i] = ldx(W, (size_t)(ot*256 + t)*64 + c, isbf);
  }
  int n0 = chunk * npts;
  float m = NEG_BIG;
  for (int s0 = 0; s0 < npts; s0 += 32){
    __syncthreads();
    const float4* src = (const float4*)(xT + ((size_t)b*N + n0 + s0)*64);
    float4* dst = (float4*)sX;
    for (int i = tid; i < 512; i += 256) dst[i] = src[i];
    __syncthreads();
    for (int t = 0; t < 32; t += 4){
      float a0=0.f, a1=0.f, a2=0.f, a3=0.f;
      #pragma unroll
      for (int c = 0; c < 64; c++){
        float wv = sW[c*256 + tid];
        a0 = fmaf(wv, sX[(t+0)*64+c], a0);
        a1 = fmaf(wv, sX[(t+1)*64+c], a1);
        a2 = fmaf(wv, sX[(t+2)*64+c], a2);
        a3 = fmaf(wv, sX[(t+3)*64+c], a3);
      }
      m = fmaxf(m, fmaxf(fmaxf(a0,a1), fmaxf(a2,a3)));
    }
  }
  int o = ot*256 + tid;
  partial[((size_t)b*1024 + o)*22 + segbase + chunk] = m;
}

__global__ void gred_kernel(const float* __restrict__ partial, float* __restrict__ g, int S){
  int i = blockIdx.x*256 + threadIdx.x;
  if (i >= 4*1024) return;
  const float* p = partial + (size_t)i*22;
  float m = NEG_BIG;
  for (int s = 0; s < S; s++) m = fmaxf(m, p[s]);
  g[i] = lrelu(m);
}

__global__ void gw_kernel(const float* __restrict__ g, const void* __restrict__ W13,
                          const int* __restrict__ dtf, float* __restrict__ gW){
  int o = blockIdx.x, b = blockIdx.y;
  int lane = threadIdx.x;
  int isbf = *dtf;
  const float* gb = g + b*1024;
  float acc = 0.f;
  for (int c = lane; c < 1024; c += 64)
    acc = fmaf(ldx(W13, (size_t)o*1088 + c, isbf), gb[c], acc);
  for (int s = 32; s > 0; s >>= 1) acc += __shfl_down(acc, s, 64);
  if (lane == 0) gW[b*256 + o] = acc;
}

// ---------------- decoder MLPs (fused unpool gather) ----------------
__global__ void mlp_kernel(const float* __restrict__ base,
    const float* __restrict__ in1, const int* __restrict__ idx1, int N1, int C1,
    const float* __restrict__ W1T,
    const float* __restrict__ in2, int C2, const float* __restrict__ W2T,
    float* __restrict__ outT, int N, int Cout){
  __shared__ float sIn[4*320];
  int o = threadIdx.x, b = blockIdx.y;
  int n0 = blockIdx.x*4;
  int Cin = C1 + C2;
  int mask1 = N1 - 1;
  for (int t = 0; t < 4; t++){
    int n = n0 + t;
    int r1 = idx1 ? (idx1[(size_t)b*N + n] & mask1) : n;
    const float* p1 = in1 + ((size_t)b*N1 + r1)*C1;
    for (int c = o; c < C1; c += Cout) sIn[t*Cin + c] = p1[c];
    if (in2){
      const float* p2 = in2 + ((size_t)b*N + n)*C2;
      for (int c = o; c < C2; c += Cout) sIn[t*Cin + C1 + c] = p2[c];
    }
  }
  __syncthreads();
  float init = base ? base[b*Cout + o] : 0.f;
  float a0 = init, a1 = init, a2 = init, a3 = init;
  for (int c = 0; c < C1; c++){
    float wv = W1T[c*Cout + o];
    a0 = fmaf(wv, sIn[0*Cin + c], a0);
    a1 = fmaf(wv, sIn[1*Cin + c], a1);
    a2 = fmaf(wv, sIn[2*Cin + c], a2);
    a3 = fmaf(wv, sIn[3*Cin + c], a3);
  }
  for (int c = 0; c < C2; c++){
    float wv = W2T[c*Cout + o];
    a0 = fmaf(wv, sIn[0*Cin + C1 + c], a0);
    a1 = fmaf(wv, sIn[1*Cin + C1 + c], a1);
    a2 = fmaf(wv, sIn[2*Cin + C1 + c], a2);
    a3 = fmaf(wv, sIn[3*Cin + C1 + c], a3);
  }
  size_t ob = ((size_t)b*N + n0)*Cout + o;
  outT[ob]          = lrelu(a0);
  outT[ob + Cout]   = lrelu(a1);
  outT[ob + 2*Cout] = lrelu(a2);
  outT[ob + 3*Cout] = lrelu(a3);
}

__global__ void dec0_kernel(const float* __restrict__ h1T, const int* __restrict__ idxU0,
                            const float* __restrict__ x0T, const float* __restrict__ W16T,
                            const void* __restrict__ W17, const int* __restrict__ dtf,
                            void* __restrict__ out){
  __shared__ float sIn[4*320];
  __shared__ float sH0[4*128];
  int o = threadIdx.x;   // 128 threads
  int b = blockIdx.y; int n0 = blockIdx.x*4;
  for (int t = 0; t < 4; t++){
    int n = n0 + t;
    int r1 = idxU0[(size_t)b*4096 + n] & 1023;
    const float* p1 = h1T + ((size_t)b*1024 + r1)*256;
    for (int c = o; c < 256; c += 128) sIn[t*320 + c] = p1[c];
    const float* p2 = x0T + ((size_t)b*4096 + n)*64;
    if (o < 64) sIn[t*320 + 256 + o] = p2[o];
  }
  __syncthreads();
  float a0 = 0.f, a1 = 0.f, a2 = 0.f, a3 = 0.f;
  for (int c = 0; c < 256; c++){
    float wv = W16T[c*128 + o];
    a0 = fmaf(wv, sIn[0*320 + c], a0);
    a1 = fmaf(wv, sIn[1*320 + c], a1);
    a2 = fmaf(wv, sIn[2*320 + c], a2);
    a3 = fmaf(wv, sIn[3*320 + c], a3);
  }
  for (int c = 0; c < 64; c++){
    float wv = W16T[(256 + c)*128 + o];
    a0 = fmaf(wv, sIn[0*320 + 256 + c], a0);
    a1 = fmaf(wv, sIn[1*320 + 256 + c], a1);
    a2 = fmaf(wv, sIn[2*320 + 256 + c], a2);
    a3 = fmaf(wv, sIn[3*320 + 256 + c], a3);
  }
  sH0[0*128 + o] = lrelu(a0);
  sH0[1*128 + o] = lrelu(a1);
  sH0[2*128 + o] = lrelu(a2);
  sH0[3*128 + o] = lrelu(a3);
  __syncthreads();
  if (o < 52){
    int isbf = *dtf;
    int p = o / 13, cc = o % 13;
    float acc = 0.f;
    for (int c2 = 0; c2 < 128; c2++)
      acc = fmaf(ldx(W17, (size_t)cc*128 + c2, isbf), sH0[p*128 + c2], acc);
    if (!(acc == acc && fabsf(acc) < 1e30f)) acc = 0.f;
    stout(out, ((size_t)b*13 + cc)*4096 + (n0 + p), acc, isbf);
  }
}

// ---------------- host ----------------
extern "C" void kernel_launch(void* const* d_in, const int* in_sizes, int n_in,
                              void* d_out, int out_size, void* d_ws, size_t ws_size,
                              hipStream_t stream){
  (void)in_sizes; (void)n_in; (void)out_size; (void)ws_size;
  const int B = 4;
  const void* X       = d_in[0];
  const void* w_ec1_0 = d_in[1];
  const void* w_ec1_1 = d_in[2];
  const void* w_ec2_0 = d_in[3];
  const void* w_ec2_1 = d_in[4];
  const void* w_ec4_0 = d_in[5];
  const void* w_ec4_1 = d_in[6];
  const void* w_ec5_0 = d_in[7];
  const void* w_ec5_1 = d_in[8];
  const void* w_ec7   = d_in[9];
  const void* w_ec8   = d_in[10];
  const void* w_ec10  = d_in[11];
  const void* w_ec11  = d_in[12];
  const void* w_pn3   = d_in[13];
  const void* w_pn6   = d_in[14];
  const void* w_pn9   = d_in[15];
  const void* w_pn12  = d_in[16];
  const void* w_pn13  = d_in[17];
  const void* w_pn14  = d_in[18];
  const void* w_pn15  = d_in[19];
  const void* w_pn16  = d_in[20];
  const void* w_c17   = d_in[21];
  void* out = d_out;

  // ---- workspace layout (fp32 words; lifetime-aliased; ~34 MB) ----
  float* wsf = (float*)d_ws;
  size_t off = 0;
  auto alloc = [&](size_t n)->float*{
    float* p = wsf + off; off += (n + 63) & ~(size_t)63; return p;
  };
  int*   dtf = (int*)alloc(64);
  float* xfT = alloc(4*4096*9);
  float* rr  = alloc(4*4096);
  float* partial = alloc(4*1024*22);
  float* g   = alloc(4*1024);
  float* gW  = alloc(4*256);
  int*   idx = (int*)alloc(4*4096*20);
  int*   idxU2 = (int*)alloc(4*256);
  int*   idxU1 = (int*)alloc(4*1024);
  int*   idxU0 = (int*)alloc(4*4096);
  float* cval = alloc(1310720);
  int*   cidx = (int*)alloc(1310720);
  float* ec1a = alloc(9*64);  float* ec1q = alloc(9*64);  float* ec1w1 = alloc(64*64);
  float* ec2a = alloc(64*64); float* ec2q = alloc(64*64); float* ec2w1 = alloc(64*64);
  float* ec4a = alloc(64*64); float* ec4q = alloc(64*64); float* ec4w1 = alloc(64*64);
  float* ec5a = alloc(64*64); float* ec5q = alloc(64*64); float* ec5w1 = alloc(64*64);
  float* ec7a = alloc(64*64); float* ec7q = alloc(64*64);
  float* ec8a = alloc(64*64); float* ec8q = alloc(64*64);
  float* ec10a = alloc(64*64); float* ec10q = alloc(64*64);
  float* ec11a = alloc(64*64); float* ec11q = alloc(64*64);
  float* wp13 = alloc(64*256);
  float* wt14 = alloc(320*256);
  float* wt15 = alloc(320*256);
  float* wt16 = alloc(320*128);
  float* P   = alloc(4*4096*64);
  float* hA  = alloc(4*4096*64);    // decoder: h1T alias (exact size)
  float* x0T = alloc(4*4096*64);
  float* x1T = alloc(4*1024*64);
  float* x2T = alloc(4*256*64);
  float* x3T = alloc(4*64*64);
  float* n1f = alloc(4*1024*64);    // decoder: h3T + head of h2T
  float* n2f = alloc(4*256*64);     // contiguous after n1f; h2T tail
  float* n3f = alloc(4*64*64);
  float* h1T = hA;
  float* h3T = n1f;
  float* h2T = n1f + 65536;

  detect_kernel<<<dim3(1), 256, 0, stream>>>((const unsigned int*)X, dtf);

  // ---- weight prep ----
  w0_kernel<<<dim3(3), 256, 0, stream>>>(w_ec1_0, dtf, 9, ec1a, ec1q);
  w0_kernel<<<dim3(16), 256, 0, stream>>>(w_ec2_0, dtf, 64, ec2a, ec2q);
  w0_kernel<<<dim3(16), 256, 0, stream>>>(w_ec4_0, dtf, 64, ec4a, ec4q);
  w0_kernel<<<dim3(16), 256, 0, stream>>>(w_ec5_0, dtf, 64, ec5a, ec5q);
  w0_kernel<<<dim3(16), 256, 0, stream>>>(w_ec7, dtf, 64, ec7a, ec7q);
  w0_kernel<<<dim3(16), 256, 0, stream>>>(w_ec8, dtf, 64, ec8a, ec8q);
  w0_kernel<<<dim3(16), 256, 0, stream>>>(w_ec10, dtf, 64, ec10a, ec10q);
  w0_kernel<<<dim3(16), 256, 0, stream>>>(w_ec11, dtf, 64, ec11a, ec11q);
  wt_kernel<<<dim3(16), 256, 0, stream>>>(w_ec1_1, dtf, 64, 64, 0, 64, ec1w1);
  wt_kernel<<<dim3(16), 256, 0, stream>>>(w_ec2_1, dtf, 64, 64, 0, 64, ec2w1);
  wt_kernel<<<dim3(16), 256, 0, stream>>>(w_ec4_1, dtf, 64, 64, 0, 64, ec4w1);
  wt_kernel<<<dim3(16), 256, 0, stream>>>(w_ec5_1, dtf, 64, 64, 0, 64, ec5w1);
  wt_kernel<<<dim3(64), 256, 0, stream>>>(w_pn13, dtf, 256, 1088, 1024, 64, wp13);
  wt_kernel<<<dim3(320), 256, 0, stream>>>(w_pn14, dtf, 256, 320, 0, 320, wt14);
  wt_kernel<<<dim3(320), 256, 0, stream>>>(w_pn15, dtf, 256, 320, 0, 320, wt15);
  wt_kernel<<<dim3(160), 256, 0, stream>>>(w_pn16, dtf, 128, 320, 0, 320, wt16);

  xconv_kernel<<<dim3(64), 256, 0, stream>>>(X, dtf, xfT);
  nodecopy_kernel<<<dim3(64), 256, 0, stream>>>(X, dtf, out);

  const size_t xbs = (size_t)4096*9;
  // coord-space kNN on xfT (pitch 9). C=9 first conv; C=3 pools/unpools.
  auto knn_f = [&](int C, int K, int M, int N, int NC, int* io){
    rownorm_kernel<<<dim3((N+255)/256, B), 256, 0, stream>>>(xfT, 9, xbs, C, N, rr);
    dim3 gd((M+255)/256, NC, B);
    if (C == 9)      knn_chunk_kernel<9,20,64><<<gd,256,0,stream>>>(xfT,9,xbs,xfT,9,xbs,rr,M,N,NC,cval,cidx);
    else if (K==20)  knn_chunk_kernel<3,20,64><<<gd,256,0,stream>>>(xfT,9,xbs,xfT,9,xbs,rr,M,N,NC,cval,cidx);
    else             knn_chunk_kernel<3,1,64><<<gd,256,0,stream>>>(xfT,9,xbs,xfT,9,xbs,rr,M,N,NC,cval,cidx);
    dim3 gm((4*M+255)/256);
    if (K == 20)     knn_merge_kernel<20><<<gm,256,0,stream>>>(cval,cidx,M,NC,io);
    else             knn_merge_kernel<1><<<gm,256,0,stream>>>(cval,cidx,M,NC,io);
  };
  // feature-space self-kNN (C=64), ref-split 4 waves
  auto knn_b = [&](int K, const float* fT, int N, int NC, int* io){
    rownorm_kernel<<<dim3((N+255)/256, B), 256, 0, stream>>>(fT, 64, (size_t)N*64, 64, N, rr);
    dim3 gd(N/64, NC, B);
    if (K == 20) knn_split64_kernel<20><<<gd,256,0,stream>>>(fT, rr, N, NC, cval, cidx);
    else         knn_split64_kernel<10><<<gd,256,0,stream>>>(fT, rr, N, NC, cval, cidx);
    dim3 gm((4*N+255)/256);
    if (K == 20) knn_merge_kernel<20><<<gm,256,0,stream>>>(cval,cidx,N,NC,io);
    else         knn_merge_kernel<10><<<gm,256,0,stream>>>(cval,cidx,N,NC,io);
  };
  auto edge2_b = [&](const float* fT, int N, int NC, float* wa, float* wq, float* w1, float* oT){
    knn_b(20, fT, N, NC, idx);
    pq_kernel<<<dim3((N+3)/4, B), 256, 0, stream>>>(fT, 64, 64, wa, P, N);
    edge2_kernel<<<dim3(N, B), 64, 0, stream>>>(P, fT, 64, 64, wq, idx, w1, oT, N, N-1);
  };
  auto edge1_b = [&](const float* fT, int N, int NC, int K, float* wa, float* wq, float* oT){
    knn_b(K, fT, N, NC, idx);
    pq_kernel<<<dim3((N+3)/4, B), 256, 0, stream>>>(fT, 64, 64, wa, P, N);
    edge1_kernel<<<dim3(N, B), 64, 0, stream>>>(P, fT, 64, 64, wq, idx, oT, N, K, N-1);
  };

  // level 0
  knn_f(9, 20, 4096, 4096, 4, idx);
  pq_kernel<<<dim3(1024, B), 256, 0, stream>>>(xfT, 9, 9, ec1a, P, 4096);
  edge2_kernel<<<dim3(4096, B), 64, 0, stream>>>(P, xfT, 9, 9, ec1q, idx, ec1w1, hA, 4096, 4095);
  edge2_b(hA, 4096, 4, ec2a, ec2q, ec2w1, x0T);
  pool_kernel<<<dim3(4,16,4), 256, 0, stream>>>(x0T, w_pn3, dtf, partial, 4096, 256, 0);
  // rand_pool 1
  knn_f(3, 20, 1024, 4096, 16, idx);
  gmax_kernel<<<dim3(1024, B), 64, 0, stream>>>(x0T, idx, n1f, 4096, 1024, 20, 4095);
  // level 1
  edge2_b(n1f, 1024, 16, ec4a, ec4q, ec4w1, hA);
  edge2_b(hA, 1024, 16, ec5a, ec5q, ec5w1, x1T);
  pool_kernel<<<dim3(4,4,4), 256, 0, stream>>>(x1T, w_pn6, dtf, partial, 1024, 256, 16);
  reluadd_kernel<<<dim3(1024), 256, 0, stream>>>(x1T, n1f, 4*1024*64);
  // rand_pool 2
  knn_f(3, 20, 256, 1024, 16, idx);
  gmax_kernel<<<dim3(256, B), 64, 0, stream>>>(x1T, idx, n2f, 1024, 256, 20, 1023);
  // level 2
  edge1_b(n2f, 256, 16, 20, ec7a, ec7q, hA);
  edge1_b(hA, 256, 16, 20, ec8a, ec8q, x2T);
  pool_kernel<<<dim3(4,1,4), 256, 0, stream>>>(x2T, w_pn9, dtf, partial, 256, 256, 20);
  reluadd_kernel<<<dim3(256), 256, 0, stream>>>(x2T, n2f, 4*256*64);
  // rand_pool 3
  knn_f(3, 20, 64, 256, 16, idx);
  gmax_kernel<<<dim3(64, B), 64, 0, stream>>>(x2T, idx, n3f, 256, 64, 20, 255);
  // level 3
  edge1_b(n3f, 64, 4, 10, ec10a, ec10q, hA);
  edge1_b(hA, 64, 4, 10, ec11a, ec11q, x3T);
  pool_kernel<<<dim3(4,1,4), 256, 0, stream>>>(x3T, w_pn12, dtf, partial, 64, 64, 21);
  reluadd_kernel<<<dim3(64), 256, 0, stream>>>(x3T, n3f, 4*64*64);
  // ---- idx, P, hA, n1f, n2f dead -> h3T/h2T/h1T aliases live ----
  gred_kernel<<<dim3(16), 256, 0, stream>>>(partial, g, 22);
  gw_kernel<<<dim3(256, 4), 64, 0, stream>>>(g, w_pn13, dtf, gW);
  mlp_kernel<<<dim3(16, B), 256, 0, stream>>>(gW, x3T, nullptr, 64, 64, wp13,
                                              nullptr, 0, nullptr, h3T, 64, 256);
  knn_f(3, 1, 256, 64, 1, idxU2);
  mlp_kernel<<<dim3(64, B), 256, 0, stream>>>(nullptr, h3T, idxU2, 64, 256, wt14,
                                              x2T, 64, wt14 + 256*256, h2T, 256, 256);
  knn_f(3, 1, 1024, 256, 4, idxU1);
  mlp_kernel<<<dim3(256, B), 256, 0, stream>>>(nullptr, h2T, idxU1, 256, 256, wt15,
                                               x1T, 64, wt15 + 256*256, h1T, 1024, 256);
  knn_f(3, 1, 4096, 1024, 4, idxU0);
  dec0_kernel<<<dim3(1024, B), 128, 0, stream>>>(h1T, idxU0, x0T, wt16, w_c17, dtf, out);
}

// Round 9
// 5771.842 us; speedup vs baseline: 1.9368x; 1.9368x over previous
//
#include <hip/hip_runtime.h>
#include <hip/hip_bf16.h>
#include <float.h>

typedef __hip_bfloat16 bf16;

#define NEG_BIG (-1.0e30f)

__device__ __forceinline__ bf16 f2b(float v){ return __float2bfloat16(v); }
__device__ __forceinline__ float lrelu(float x){ return x >= 0.f ? x : 0.2f*x; }

// dtype-flexible sanitized load from a raw INPUT buffer (element index)
__device__ __forceinline__ float ldx(const void* p, size_t i, int isbf){
  float v = isbf ? __bfloat162float(((const bf16*)p)[i]) : ((const float*)p)[i];
  return (v == v && fabsf(v) < 1e30f) ? v : 0.f;
}
// dtype-flexible store to the OUTPUT buffer (element index)
__device__ __forceinline__ void stout(void* p, size_t i, float v, int isbf){
  if (isbf) ((bf16*)p)[i] = f2b(v);
  else      ((float*)p)[i] = v;
}

// ---------------- input dtype detector ----------------
__global__ void detect_kernel(const unsigned int* __restrict__ X, int* __restrict__ flag){
  __shared__ int cnt;
  if (threadIdx.x == 0) cnt = 0;
  __syncthreads();
  int hits = 0;
  for (int i = threadIdx.x; i < 8192; i += 256){
    unsigned w = X[i];
    unsigned lo = w & 0xFFFFu;
    unsigned e = (lo >> 7) & 0xFFu;
    if ((e >= 0x76u && e <= 0x84u) || lo == 0u) hits++;
  }
  atomicAdd(&cnt, hits);
  __syncthreads();
  if (threadIdx.x == 0) flag[0] = (cnt > 4096) ? 1 : 0;
}

// ---------------- weight prep ----------------
__global__ void wt_kernel(const void* __restrict__ W, const int* __restrict__ dtf,
                          int Cout, int pitch, int coff, int Cin, float* __restrict__ WT){
  int i = blockIdx.x*256 + threadIdx.x;
  if (i >= Cin*Cout) return;
  int isbf = *dtf;
  int c = i / Cout, o = i - c*Cout;
  WT[i] = ldx(W, (size_t)o*pitch + coff + c, isbf);
}

__global__ void w0_kernel(const void* __restrict__ W0, const int* __restrict__ dtf,
                          int C, float* __restrict__ WaT, float* __restrict__ WqT){
  int i = blockIdx.x*256 + threadIdx.x;
  if (i >= C*64) return;
  int isbf = *dtf;
  int c = i >> 6, o = i & 63;
  float a = ldx(W0, (size_t)o*2*C + c, isbf);
  float q = ldx(W0, (size_t)o*2*C + C + c, isbf);
  WaT[i] = a; WqT[i] = q - a;
}

__global__ void xconv_kernel(const void* __restrict__ x, const int* __restrict__ dtf,
                             float* __restrict__ xfT){
  int i = blockIdx.x*256 + threadIdx.x;
  if (i >= 4*4096) return;
  int isbf = *dtf;
  int b = i >> 12, n = i & 4095;
  for (int c = 0; c < 9; c++)
    xfT[((size_t)b*4096 + n)*9 + c] = ldx(x, ((size_t)b*9 + c)*4096 + n, isbf);
}

__global__ void nodecopy_kernel(const void* __restrict__ x, const int* __restrict__ dtf,
                                void* __restrict__ out){
  int i = blockIdx.x*256 + threadIdx.x;
  int isbf = *dtf;
  if (i < 12288){
    int b = i / 3072, r = i % 3072; int c = r / 1024, m = r % 1024;
    stout(out, 212992 + i, ldx(x, ((size_t)b*9 + c)*4096 + m, isbf), isbf);
  } else if (i < 15360){
    int j = i - 12288; int b = j / 768, r = j % 768; int c = r / 256, m = r % 256;
    stout(out, 212992 + i, ldx(x, ((size_t)b*9 + c)*4096 + m, isbf), isbf);
  } else if (i < 16128){
    int j = i - 15360; int b = j / 192, r = j % 192; int c = r / 64, m = r % 64;
    stout(out, 212992 + i, ldx(x, ((size_t)b*9 + c)*4096 + m, isbf), isbf);
  }
}

// ---------------- kNN ----------------
__global__ void rownorm_kernel(const float* __restrict__ T, int pitch, size_t bs,
                               int C, int N, float* __restrict__ rr){
  int n = blockIdx.x*256 + threadIdx.x;
  int b = blockIdx.y;
  if (n >= N) return;
  const float* row = T + (size_t)b*bs + (size_t)n*pitch;
  float s = 0.f;
  for (int c = 0; c < C; c++) s = fmaf(row[c], row[c], s);
  rr[b*N + n] = s;
}

// small-C chunked kNN (C=3/9; per-thread query in registers, refs staged in LDS)
// REQUIREMENT: len = N/NC must be a multiple of TN.
template<int C, int K, int TN>
__global__ void knn_chunk_kernel(const float* __restrict__ qT, int qpitch, size_t qbs,
                                 const float* __restrict__ rT, int rpitch, size_t rbs,
                                 const float* __restrict__ rr, int M, int N, int NC,
                                 float* __restrict__ cval, int* __restrict__ cidx){
  __shared__ float sR[TN*C];
  __shared__ float sN[TN];
  int tid = threadIdx.x;
  int m = blockIdx.x*256 + tid;
  int cid = blockIdx.y, b = blockIdx.z;
  int len = N / NC;
  int n0 = cid * len;
  bool active = (m < M);
  float q[C]; float qq = 0.f;
  if (active){
    const float* qrow = qT + (size_t)b*qbs + (size_t)m*qpitch;
    #pragma unroll
    for (int c = 0; c < C; c++){ q[c] = qrow[c]; qq = fmaf(q[c], q[c], qq); }
  }
  float bv[K]; int bi[K];
  #pragma unroll
  for (int j = 0; j < K; j++){ bv[j] = NEG_BIG; bi[j] = n0; }
  float minv = NEG_BIG; int minpos = 0;
  auto ins = [&](float d, int j){
    if (d > minv){
      #pragma unroll
      for (int s = 0; s < K; s++) if (s == minpos){ bv[s] = d; bi[s] = j; }
      minv = bv[0]; minpos = 0;
      #pragma unroll
      for (int s = 1; s < K; s++) if (bv[s] < minv){ minv = bv[s]; minpos = s; }
    }
  };
  const float* rbase = rT + (size_t)b*rbs;
  const float* rrb = rr + b*N;
  for (int t0 = 0; t0 < len; t0 += TN){
    __syncthreads();
    for (int i = tid; i < TN*C; i += 256){
      int t = i / C, c = i - t*C;
      sR[i] = rbase[(size_t)(n0 + t0 + t)*rpitch + c];
    }
    for (int i = tid; i < TN; i += 256) sN[i] = rrb[n0 + t0 + i];
    __syncthreads();
    if (active){
      for (int t = 0; t < TN; t += 4){
        float a0 = 0.f, a1 = 0.f, a2 = 0.f, a3 = 0.f;
        #pragma unroll
        for (int c = 0; c < C; c++){
          float qc = q[c];
          a0 = fmaf(qc, sR[(t+0)*C + c], a0);
          a1 = fmaf(qc, sR[(t+1)*C + c], a1);
          a2 = fmaf(qc, sR[(t+2)*C + c], a2);
          a3 = fmaf(qc, sR[(t+3)*C + c], a3);
        }
        int jb = n0 + t0 + t;
        ins(2.f*a0 - qq - sN[t+0], jb+0);
        ins(2.f*a1 - qq - sN[t+1], jb+1);
        ins(2.f*a2 - qq - sN[t+2], jb+2);
        ins(2.f*a3 - qq - sN[t+3], jb+3);
      }
    }
  }
  if (active){
    float* ov = cval + ((size_t)((size_t)b*M + m)*NC + cid)*K;
    int*   oi = cidx + ((size_t)((size_t)b*M + m)*NC + cid)*K;
    #pragma unroll
    for (int j = 0; j < K; j++){ ov[j] = bv[j]; oi[j] = bi[j]; }
  }
}

// C=64 self-kNN, R6-proven no-spill scan kernel, 64-thread (1-wave) blocks:
// 64 queries staged in LDS (pad 65); refs read wave-uniform float4 (L1
// broadcast); scan chunk cid; write per-chunk top-K candidates; merge is a
// SEPARATE kernel (any in-kernel merge phase provably triggers scratch spill).
template<int K>
__global__ void knn64_kernel(const float* __restrict__ fT, const float* __restrict__ rr,
                             int N, int NC, float* __restrict__ cval, int* __restrict__ cidx){
  __shared__ float sQ[64*65];
  int lane = threadIdx.x;
  int q0 = blockIdx.x*64;
  int cid = blockIdx.y, b = blockIdx.z;
  int m = q0 + lane;
  int len = N / NC;
  int n0 = cid*len;
  // stage 64 query rows (float4 global loads, scalar LDS writes due to pad)
  for (int i = lane; i < 64*16; i += 64){
    int qi = i >> 4, c4 = i & 15;
    float4 v = ((const float4*)(fT + ((size_t)b*N + q0 + qi)*64))[c4];
    float* dst = sQ + qi*65 + c4*4;
    dst[0] = v.x; dst[1] = v.y; dst[2] = v.z; dst[3] = v.w;
  }
  __syncthreads();
  float qq = rr[(size_t)b*N + m];   // self-kNN (M==N)
  float bv[K]; int bi[K];
  #pragma unroll
  for (int j = 0; j < K; j++){ bv[j] = NEG_BIG; bi[j] = n0; }
  float minv = NEG_BIG; int minpos = 0;
  auto ins = [&](float d, int j){
    if (d > minv){
      #pragma unroll
      for (int s = 0; s < K; s++) if (s == minpos){ bv[s] = d; bi[s] = j; }
      minv = bv[0]; minpos = 0;
      #pragma unroll
      for (int s = 1; s < K; s++) if (bv[s] < minv){ minv = bv[s]; minpos = s; }
    }
  };
  const float4* rbase = (const float4*)(fT + ((size_t)b*N + n0)*64);
  const float* rrb = rr + (size_t)b*N + n0;
  const float* qrow = sQ + lane*65;
  for (int t0 = 0; t0 < len; t0 += 4){
    const float4* r4 = rbase + (size_t)t0*16;
    float a0=0.f, a1=0.f, a2=0.f, a3=0.f;
    #pragma unroll
    for (int ct = 0; ct < 16; ct++){
      float4 v0 = r4[ct], v1 = r4[16+ct], v2 = r4[32+ct], v3 = r4[48+ct];
      float qa = qrow[ct*4+0], qb = qrow[ct*4+1], qc = qrow[ct*4+2], qd = qrow[ct*4+3];
      a0 = fmaf(qa,v0.x,a0); a0 = fmaf(qb,v0.y,a0); a0 = fmaf(qc,v0.z,a0); a0 = fmaf(qd,v0.w,a0);
      a1 = fmaf(qa,v1.x,a1); a1 = fmaf(qb,v1.y,a1); a1 = fmaf(qc,v1.z,a1); a1 = fmaf(qd,v1.w,a1);
      a2 = fmaf(qa,v2.x,a2); a2 = fmaf(qb,v2.y,a2); a2 = fmaf(qc,v2.z,a2); a2 = fmaf(qd,v2.w,a2);
      a3 = fmaf(qa,v3.x,a3); a3 = fmaf(qb,v3.y,a3); a3 = fmaf(qc,v3.z,a3); a3 = fmaf(qd,v3.w,a3);
    }
    ins(2.f*a0 - qq - rrb[t0+0], n0+t0+0);
    ins(2.f*a1 - qq - rrb[t0+1], n0+t0+1);
    ins(2.f*a2 - qq - rrb[t0+2], n0+t0+2);
    ins(2.f*a3 - qq - rrb[t0+3], n0+t0+3);
  }
  float* ov = cval + ((size_t)((size_t)b*N + m)*NC + cid)*K;
  int*   oi = cidx + ((size_t)((size_t)b*N + m)*NC + cid)*K;
  #pragma unroll
  for (int j = 0; j < K; j++){ ov[j] = bv[j]; oi[j] = bi[j]; }
}

template<int K>
__global__ void knn_merge_kernel(const float* __restrict__ cval, const int* __restrict__ cidx,
                                 int M, int NC, int* __restrict__ idxo){
  int i = blockIdx.x*256 + threadIdx.x;   // b*M + m
  if (i >= 4*M) return;
  const float* cv = cval + (size_t)i*NC*K;
  const int*   ci = cidx + (size_t)i*NC*K;
  float bv[K]; int bi[K];
  #pragma unroll
  for (int j = 0; j < K; j++){ bv[j] = NEG_BIG; bi[j] = 0; }
  float minv = NEG_BIG; int minpos = 0;
  int T = NC*K;
  for (int t = 0; t < T; t++){
    float d = cv[t];
    if (d > minv){
      int j = ci[t];
      #pragma unroll
      for (int s = 0; s < K; s++) if (s == minpos){ bv[s] = d; bi[s] = j; }
      minv = bv[0]; minpos = 0;
      #pragma unroll
      for (int s = 1; s < K; s++) if (bv[s] < minv){ minv = bv[s]; minpos = s; }
    }
  }
  int* orow = idxo + (size_t)i*K;
  #pragma unroll
  for (int j = 0; j < K; j++) orow[j] = bi[j];
}

// ---------------- edge conv ----------------
__global__ void pq_kernel(const float* __restrict__ xT, int pitch, int C,
                          const float* __restrict__ WaT,
                          float* __restrict__ P, int N){
  int o = threadIdx.x & 63;
  int n = blockIdx.x*4 + (threadIdx.x >> 6);
  int b = blockIdx.y;
  if (n >= N) return;
  const float* row = xT + ((size_t)b*N + n)*pitch;
  float ap = 0.f;
  for (int c = 0; c < C; c++) ap = fmaf(WaT[c*64 + o], row[c], ap);
  P[((size_t)b*N + n)*64 + o] = ap;
}

__global__ void edge2_kernel(const float* __restrict__ P, const float* __restrict__ featT,
                             int pitch, int C, const float* __restrict__ WqT,
                             const int* __restrict__ idx, const float* __restrict__ W1T,
                             float* __restrict__ outT, int N, int mask){
  __shared__ float sW[64*64];
  __shared__ float sH[20*64];
  __shared__ float sx[64];
  int o = threadIdx.x; int n = blockIdx.x; int b = blockIdx.y;
  const float4* w4 = (const float4*)W1T;
  float4* s4 = (float4*)sW;
  #pragma unroll
  for (int i = 0; i < 16; i++) s4[i*64 + o] = w4[i*64 + o];
  if (o < C) sx[o] = featT[((size_t)b*N + n)*pitch + o];
  __syncthreads();
  float qv = 0.f;
  for (int c = 0; c < C; c++) qv = fmaf(WqT[c*64 + o], sx[c], qv);
  const float* Pb = P + (size_t)b*N*64;
  const int* irow = idx + ((size_t)b*N + n)*20;
  for (int kk = 0; kk < 20; kk++){
    int j = irow[kk] & mask;
    float h = Pb[(size_t)j*64 + o] + qv;
    sH[kk*64 + o] = h >= 0.f ? h : 0.2f*h;
  }
  __syncthreads();
  float acc[20];
  #pragma unroll
  for (int kk = 0; kk < 20; kk++) acc[kk] = 0.f;
  for (int c = 0; c < 64; c += 4){
    float w0 = sW[c*64+o], w1 = sW[(c+1)*64+o], w2 = sW[(c+2)*64+o], w3 = sW[(c+3)*64+o];
    #pragma unroll
    for (int kk = 0; kk < 20; kk++){
      float4 h4 = *(const float4*)&sH[kk*64 + c];
      float a = acc[kk];
      a = fmaf(w0, h4.x, a); a = fmaf(w1, h4.y, a);
      a = fmaf(w2, h4.z, a); a = fmaf(w3, h4.w, a);
      acc[kk] = a;
    }
  }
  float m = NEG_BIG;
  #pragma unroll
  for (int kk = 0; kk < 20; kk++) m = fmaxf(m, acc[kk]);
  outT[((size_t)b*N + n)*64 + o] = lrelu(m);
}

__global__ void edge1_kernel(const float* __restrict__ P, const float* __restrict__ featT,
                             int pitch, int C, const float* __restrict__ WqT,
                             const int* __restrict__ idx, float* __restrict__ outT,
                             int N, int K, int mask){
  __shared__ float sx[64];
  int o = threadIdx.x; int n = blockIdx.x; int b = blockIdx.y;
  if (o < C) sx[o] = featT[((size_t)b*N + n)*pitch + o];
  __syncthreads();
  float qv = 0.f;
  for (int c = 0; c < C; c++) qv = fmaf(WqT[c*64 + o], sx[c], qv);
  const float* Pb = P + (size_t)b*N*64;
  const int* irow = idx + ((size_t)b*N + n)*K;
  float m = NEG_BIG;
  for (int kk = 0; kk < K; kk++){
    int j = irow[kk] & mask;
    m = fmaxf(m, Pb[(size_t)j*64 + o] + qv);
  }
  outT[((size_t)b*N + n)*64 + o] = lrelu(m);
}

__global__ void gmax_kernel(const float* __restrict__ inT, const int* __restrict__ idx,
                            float* __restrict__ outT, int Nin, int M, int K, int mask){
  int o = threadIdx.x; int m = blockIdx.x; int b = blockIdx.y;
  const float* ib = inT + (size_t)b*Nin*64;
  const int* irow = idx + ((size_t)b*M + m)*K;
  float v = NEG_BIG;
  for (int kk = 0; kk < K; kk++){
    int j = irow[kk] & mask;
    v = fmaxf(v, ib[(size_t)j*64 + o]);
  }
  outT[((size_t)b*M + m)*64 + o] = v;
}

__global__ void reluadd_kernel(float* __restrict__ x, const float* __restrict__ f, int total){
  int i = blockIdx.x*256 + threadIdx.x;
  if (i >= total) return;
  float v = x[i] + f[i];
  x[i] = v > 0.f ? v : 0.f;
}

// ---------------- global feature path ----------------
__global__ void pool_kernel(const float* __restrict__ xT, const void* __restrict__ W,
                            const int* __restrict__ dtf, float* __restrict__ partial,
                            int N, int npts, int segbase){
  __shared__ float sW[64*256];
  __shared__ float sX[32*64];
  int tid = threadIdx.x;
  int ot = blockIdx.x, chunk = blockIdx.y, b = blockIdx.z;
  int isbf = *dtf;
  for (int i = tid; i < 64*256; i += 256){
    int c = i >> 8, t = i & 255;
    sW[i] = ldx(W, (size_t)(ot*256 + t)*64 + c, isbf);
  }
  int n0 = chunk * npts;
  float m = NEG_BIG;
  for (int s0 = 0; s0 < npts; s0 += 32){
    __syncthreads();
    const float4* src = (const float4*)(xT + ((size_t)b*N + n0 + s0)*64);
    float4* dst = (float4*)sX;
    for (int i = tid; i < 512; i += 256) dst[i] = src[i];
    __syncthreads();
    for (int t = 0; t < 32; t += 4){
      float a0=0.f, a1=0.f, a2=0.f, a3=0.f;
      #pragma unroll
      for (int c = 0; c < 64; c++){
        float wv = sW[c*256 + tid];
        a0 = fmaf(wv, sX[(t+0)*64+c], a0);
        a1 = fmaf(wv, sX[(t+1)*64+c], a1);
        a2 = fmaf(wv, sX[(t+2)*64+c], a2);
        a3 = fmaf(wv, sX[(t+3)*64+c], a3);
      }
      m = fmaxf(m, fmaxf(fmaxf(a0,a1), fmaxf(a2,a3)));
    }
  }
  int o = ot*256 + tid;
  partial[((size_t)b*1024 + o)*22 + segbase + chunk] = m;
}

__global__ void gred_kernel(const float* __restrict__ partial, float* __restrict__ g, int S){
  int i = blockIdx.x*256 + threadIdx.x;
  if (i >= 4*1024) return;
  const float* p = partial + (size_t)i*22;
  float m = NEG_BIG;
  for (int s = 0; s < S; s++) m = fmaxf(m, p[s]);
  g[i] = lrelu(m);
}

__global__ void gw_kernel(const float* __restrict__ g, const void* __restrict__ W13,
                          const int* __restrict__ dtf, float* __restrict__ gW){
  int o = blockIdx.x, b = blockIdx.y;
  int lane = threadIdx.x;
  int isbf = *dtf;
  const float* gb = g + b*1024;
  float acc = 0.f;
  for (int c = lane; c < 1024; c += 64)
    acc = fmaf(ldx(W13, (size_t)o*1088 + c, isbf), gb[c], acc);
  for (int s = 32; s > 0; s >>= 1) acc += __shfl_down(acc, s, 64);
  if (lane == 0) gW[b*256 + o] = acc;
}

// ---------------- decoder MLPs (fused unpool gather) ----------------
__global__ void mlp_kernel(const float* __restrict__ base,
    const float* __restrict__ in1, const int* __restrict__ idx1, int N1, int C1,
    const float* __restrict__ W1T,
    const float* __restrict__ in2, int C2, const float* __restrict__ W2T,
    float* __restrict__ outT, int N, int Cout){
  __shared__ float sIn[4*320];
  int o = threadIdx.x, b = blockIdx.y;
  int n0 = blockIdx.x*4;
  int Cin = C1 + C2;
  int mask1 = N1 - 1;
  for (int t = 0; t < 4; t++){
    int n = n0 + t;
    int r1 = idx1 ? (idx1[(size_t)b*N + n] & mask1) : n;
    const float* p1 = in1 + ((size_t)b*N1 + r1)*C1;
    for (int c = o; c < C1; c += Cout) sIn[t*Cin + c] = p1[c];
    if (in2){
      const float* p2 = in2 + ((size_t)b*N + n)*C2;
      for (int c = o; c < C2; c += Cout) sIn[t*Cin + C1 + c] = p2[c];
    }
  }
  __syncthreads();
  float init = base ? base[b*Cout + o] : 0.f;
  float a0 = init, a1 = init, a2 = init, a3 = init;
  for (int c = 0; c < C1; c++){
    float wv = W1T[c*Cout + o];
    a0 = fmaf(wv, sIn[0*Cin + c], a0);
    a1 = fmaf(wv, sIn[1*Cin + c], a1);
    a2 = fmaf(wv, sIn[2*Cin + c], a2);
    a3 = fmaf(wv, sIn[3*Cin + c], a3);
  }
  for (int c = 0; c < C2; c++){
    float wv = W2T[c*Cout + o];
    a0 = fmaf(wv, sIn[0*Cin + C1 + c], a0);
    a1 = fmaf(wv, sIn[1*Cin + C1 + c], a1);
    a2 = fmaf(wv, sIn[2*Cin + C1 + c], a2);
    a3 = fmaf(wv, sIn[3*Cin + C1 + c], a3);
  }
  size_t ob = ((size_t)b*N + n0)*Cout + o;
  outT[ob]          = lrelu(a0);
  outT[ob + Cout]   = lrelu(a1);
  outT[ob + 2*Cout] = lrelu(a2);
  outT[ob + 3*Cout] = lrelu(a3);
}

__global__ void dec0_kernel(const float* __restrict__ h1T, const int* __restrict__ idxU0,
                            const float* __restrict__ x0T, const float* __restrict__ W16T,
                            const void* __restrict__ W17, const int* __restrict__ dtf,
                            void* __restrict__ out){
  __shared__ float sIn[4*320];
  __shared__ float sH0[4*128];
  int o = threadIdx.x;   // 128 threads
  int b = blockIdx.y; int n0 = blockIdx.x*4;
  for (int t = 0; t < 4; t++){
    int n = n0 + t;
    int r1 = idxU0[(size_t)b*4096 + n] & 1023;
    const float* p1 = h1T + ((size_t)b*1024 + r1)*256;
    for (int c = o; c < 256; c += 128) sIn[t*320 + c] = p1[c];
    const float* p2 = x0T + ((size_t)b*4096 + n)*64;
    if (o < 64) sIn[t*320 + 256 + o] = p2[o];
  }
  __syncthreads();
  float a0 = 0.f, a1 = 0.f, a2 = 0.f, a3 = 0.f;
  for (int c = 0; c < 256; c++){
    float wv = W16T[c*128 + o];
    a0 = fmaf(wv, sIn[0*320 + c], a0);
    a1 = fmaf(wv, sIn[1*320 + c], a1);
    a2 = fmaf(wv, sIn[2*320 + c], a2);
    a3 = fmaf(wv, sIn[3*320 + c], a3);
  }
  for (int c = 0; c < 64; c++){
    float wv = W16T[(256 + c)*128 + o];
    a0 = fmaf(wv, sIn[0*320 + 256 + c], a0);
    a1 = fmaf(wv, sIn[1*320 + 256 + c], a1);
    a2 = fmaf(wv, sIn[2*320 + 256 + c], a2);
    a3 = fmaf(wv, sIn[3*320 + 256 + c], a3);
  }
  sH0[0*128 + o] = lrelu(a0);
  sH0[1*128 + o] = lrelu(a1);
  sH0[2*128 + o] = lrelu(a2);
  sH0[3*128 + o] = lrelu(a3);
  __syncthreads();
  if (o < 52){
    int isbf = *dtf;
    int p = o / 13, cc = o % 13;
    float acc = 0.f;
    for (int c2 = 0; c2 < 128; c2++)
      acc = fmaf(ldx(W17, (size_t)cc*128 + c2, isbf), sH0[p*128 + c2], acc);
    if (!(acc == acc && fabsf(acc) < 1e30f)) acc = 0.f;
    stout(out, ((size_t)b*13 + cc)*4096 + (n0 + p), acc, isbf);
  }
}

// ---------------- host ----------------
extern "C" void kernel_launch(void* const* d_in, const int* in_sizes, int n_in,
                              void* d_out, int out_size, void* d_ws, size_t ws_size,
                              hipStream_t stream){
  (void)in_sizes; (void)n_in; (void)out_size;
  const int B = 4;
  const void* X       = d_in[0];
  const void* w_ec1_0 = d_in[1];
  const void* w_ec1_1 = d_in[2];
  const void* w_ec2_0 = d_in[3];
  const void* w_ec2_1 = d_in[4];
  const void* w_ec4_0 = d_in[5];
  const void* w_ec4_1 = d_in[6];
  const void* w_ec5_0 = d_in[7];
  const void* w_ec5_1 = d_in[8];
  const void* w_ec7   = d_in[9];
  const void* w_ec8   = d_in[10];
  const void* w_ec10  = d_in[11];
  const void* w_ec11  = d_in[12];
  const void* w_pn3   = d_in[13];
  const void* w_pn6   = d_in[14];
  const void* w_pn9   = d_in[15];
  const void* w_pn12  = d_in[16];
  const void* w_pn13  = d_in[17];
  const void* w_pn14  = d_in[18];
  const void* w_pn15  = d_in[19];
  const void* w_pn16  = d_in[20];
  const void* w_c17   = d_in[21];
  void* out = d_out;

  // ---- workspace layout (fp32 words; lifetime-aliased) ----
  float* wsf = (float*)d_ws;
  size_t off = 0;
  auto alloc = [&](size_t n)->float*{
    float* p = wsf + off; off += (n + 63) & ~(size_t)63; return p;
  };
  int*   dtf = (int*)alloc(64);
  float* xfT = alloc(4*4096*9);
  float* rr  = alloc(4*4096);
  float* partial = alloc(4*1024*22);
  float* g   = alloc(4*1024);
  float* gW  = alloc(4*256);
  int*   idx = (int*)alloc(4*4096*20);
  int*   idxU2 = (int*)alloc(4*256);
  int*   idxU1 = (int*)alloc(4*1024);
  int*   idxU0 = (int*)alloc(4*4096);
  float* ec1a = alloc(9*64);  float* ec1q = alloc(9*64);  float* ec1w1 = alloc(64*64);
  float* ec2a = alloc(64*64); float* ec2q = alloc(64*64); float* ec2w1 = alloc(64*64);
  float* ec4a = alloc(64*64); float* ec4q = alloc(64*64); float* ec4w1 = alloc(64*64);
  float* ec5a = alloc(64*64); float* ec5q = alloc(64*64); float* ec5w1 = alloc(64*64);
  float* ec7a = alloc(64*64); float* ec7q = alloc(64*64);
  float* ec8a = alloc(64*64); float* ec8q = alloc(64*64);
  float* ec10a = alloc(64*64); float* ec10q = alloc(64*64);
  float* ec11a = alloc(64*64); float* ec11q = alloc(64*64);
  float* wp13 = alloc(64*256);
  float* wt14 = alloc(320*256);
  float* wt15 = alloc(320*256);
  float* wt16 = alloc(320*128);
  float* P   = alloc(4*4096*64);
  float* hA  = alloc(4*4096*64);    // decoder: h1T alias (exact size)
  float* x0T = alloc(4*4096*64);
  float* x1T = alloc(4*1024*64);
  float* x2T = alloc(4*256*64);
  float* x3T = alloc(4*64*64);
  float* n1f = alloc(4*1024*64);    // decoder: h3T + head of h2T
  float* n2f = alloc(4*256*64);     // contiguous after n1f; h2T tail
  float* n3f = alloc(4*64*64);
  float* h1T = hA;
  float* h3T = n1f;
  float* h2T = n1f + 65536;

  // ws-aware candidate sizing: pick NCbig by remaining scratch.
  // ws_size is constant across calls -> deterministic work per call.
  size_t rem = (ws_size/4 > off + 256) ? (ws_size/4 - off - 256) : 0;
  size_t half = rem / 2;
  int NCbig = (half >= (size_t)4*4096*16*20) ? 16 :
              (half >= (size_t)4*4096*8*20)  ? 8  : 4;
  size_t E = (size_t)4*4096*20*NCbig;
  float* cval = alloc(E);
  int*   cidx = (int*)alloc(E);

  detect_kernel<<<dim3(1), 256, 0, stream>>>((const unsigned int*)X, dtf);

  // ---- weight prep ----
  w0_kernel<<<dim3(3), 256, 0, stream>>>(w_ec1_0, dtf, 9, ec1a, ec1q);
  w0_kernel<<<dim3(16), 256, 0, stream>>>(w_ec2_0, dtf, 64, ec2a, ec2q);
  w0_kernel<<<dim3(16), 256, 0, stream>>>(w_ec4_0, dtf, 64, ec4a, ec4q);
  w0_kernel<<<dim3(16), 256, 0, stream>>>(w_ec5_0, dtf, 64, ec5a, ec5q);
  w0_kernel<<<dim3(16), 256, 0, stream>>>(w_ec7, dtf, 64, ec7a, ec7q);
  w0_kernel<<<dim3(16), 256, 0, stream>>>(w_ec8, dtf, 64, ec8a, ec8q);
  w0_kernel<<<dim3(16), 256, 0, stream>>>(w_ec10, dtf, 64, ec10a, ec10q);
  w0_kernel<<<dim3(16), 256, 0, stream>>>(w_ec11, dtf, 64, ec11a, ec11q);
  wt_kernel<<<dim3(16), 256, 0, stream>>>(w_ec1_1, dtf, 64, 64, 0, 64, ec1w1);
  wt_kernel<<<dim3(16), 256, 0, stream>>>(w_ec2_1, dtf, 64, 64, 0, 64, ec2w1);
  wt_kernel<<<dim3(16), 256, 0, stream>>>(w_ec4_1, dtf, 64, 64, 0, 64, ec4w1);
  wt_kernel<<<dim3(16), 256, 0, stream>>>(w_ec5_1, dtf, 64, 64, 0, 64, ec5w1);
  wt_kernel<<<dim3(64), 256, 0, stream>>>(w_pn13, dtf, 256, 1088, 1024, 64, wp13);
  wt_kernel<<<dim3(320), 256, 0, stream>>>(w_pn14, dtf, 256, 320, 0, 320, wt14);
  wt_kernel<<<dim3(320), 256, 0, stream>>>(w_pn15, dtf, 256, 320, 0, 320, wt15);
  wt_kernel<<<dim3(160), 256, 0, stream>>>(w_pn16, dtf, 128, 320, 0, 320, wt16);

  xconv_kernel<<<dim3(64), 256, 0, stream>>>(X, dtf, xfT);
  nodecopy_kernel<<<dim3(64), 256, 0, stream>>>(X, dtf, out);

  const size_t xbs = (size_t)4096*9;
  // coord-space kNN on xfT (pitch 9). len=N/NC must be multiple of 64.
  auto knn_f = [&](int C, int K, int M, int N, int NC, int* io){
    rownorm_kernel<<<dim3((N+255)/256, B), 256, 0, stream>>>(xfT, 9, xbs, C, N, rr);
    dim3 gd((M+255)/256, NC, B);
    if (C == 9)      knn_chunk_kernel<9,20,64><<<gd,256,0,stream>>>(xfT,9,xbs,xfT,9,xbs,rr,M,N,NC,cval,cidx);
    else if (K==20)  knn_chunk_kernel<3,20,64><<<gd,256,0,stream>>>(xfT,9,xbs,xfT,9,xbs,rr,M,N,NC,cval,cidx);
    else             knn_chunk_kernel<3,1,64><<<gd,256,0,stream>>>(xfT,9,xbs,xfT,9,xbs,rr,M,N,NC,cval,cidx);
    dim3 gm((4*M+255)/256);
    if (K == 20)     knn_merge_kernel<20><<<gm,256,0,stream>>>(cval,cidx,M,NC,io);
    else             knn_merge_kernel<1><<<gm,256,0,stream>>>(cval,cidx,M,NC,io);
  };
  // feature-space self-kNN (C=64), 1-wave blocks, 64 queries each
  auto knn_b = [&](int K, const float* fT, int N, int NC, int* io){
    rownorm_kernel<<<dim3((N+255)/256, B), 256, 0, stream>>>(fT, 64, (size_t)N*64, 64, N, rr);
    dim3 gd(N/64, NC, B);
    if (K == 20) knn64_kernel<20><<<gd,64,0,stream>>>(fT, rr, N, NC, cval, cidx);
    else         knn64_kernel<10><<<gd,64,0,stream>>>(fT, rr, N, NC, cval, cidx);
    dim3 gm((4*N+255)/256);
    if (K == 20) knn_merge_kernel<20><<<gm,256,0,stream>>>(cval,cidx,N,NC,io);
    else         knn_merge_kernel<10><<<gm,256,0,stream>>>(cval,cidx,N,NC,io);
  };
  auto edge2_b = [&](const float* fT, int N, int NC, float* wa, float* wq, float* w1, float* oT){
    knn_b(20, fT, N, NC, idx);
    pq_kernel<<<dim3((N+3)/4, B), 256, 0, stream>>>(fT, 64, 64, wa, P, N);
    edge2_kernel<<<dim3(N, B), 64, 0, stream>>>(P, fT, 64, 64, wq, idx, w1, oT, N, N-1);
  };
  auto edge1_b = [&](const float* fT, int N, int NC, int K, float* wa, float* wq, float* oT){
    knn_b(K, fT, N, NC, idx);
    pq_kernel<<<dim3((N+3)/4, B), 256, 0, stream>>>(fT, 64, 64, wa, P, N);
    edge1_kernel<<<dim3(N, B), 64, 0, stream>>>(P, fT, 64, 64, wq, idx, oT, N, K, N-1);
  };

  // level 0
  knn_f(9, 20, 4096, 4096, NCbig, idx);                  // len = 4096/NCbig ≥ 256
  pq_kernel<<<dim3(1024, B), 256, 0, stream>>>(xfT, 9, 9, ec1a, P, 4096);
  edge2_kernel<<<dim3(4096, B), 64, 0, stream>>>(P, xfT, 9, 9, ec1q, idx, ec1w1, hA, 4096, 4095);
  edge2_b(hA, 4096, NCbig, ec2a, ec2q, ec2w1, x0T);
  pool_kernel<<<dim3(4,16,4), 256, 0, stream>>>(x0T, w_pn3, dtf, partial, 4096, 256, 0);
  // rand_pool 1
  knn_f(3, 20, 1024, 4096, 16, idx);                     // len 256
  gmax_kernel<<<dim3(1024, B), 64, 0, stream>>>(x0T, idx, n1f, 4096, 1024, 20, 4095);
  // level 1
  edge2_b(n1f, 1024, 16, ec4a, ec4q, ec4w1, hA);
  edge2_b(hA, 1024, 16, ec5a, ec5q, ec5w1, x1T);
  pool_kernel<<<dim3(4,4,4), 256, 0, stream>>>(x1T, w_pn6, dtf, partial, 1024, 256, 16);
  reluadd_kernel<<<dim3(1024), 256, 0, stream>>>(x1T, n1f, 4*1024*64);
  // rand_pool 2
  knn_f(3, 20, 256, 1024, 16, idx);                      // len 64
  gmax_kernel<<<dim3(256, B), 64, 0, stream>>>(x1T, idx, n2f, 1024, 256, 20, 1023);
  // level 2
  edge1_b(n2f, 256, 16, 20, ec7a, ec7q, hA);             // len 16 (knn64: mult of 4 OK)
  edge1_b(hA, 256, 16, 20, ec8a, ec8q, x2T);
  pool_kernel<<<dim3(4,1,4), 256, 0, stream>>>(x2T, w_pn9, dtf, partial, 256, 256, 20);
  reluadd_kernel<<<dim3(256), 256, 0, stream>>>(x2T, n2f, 4*256*64);
  // rand_pool 3
  knn_f(3, 20, 64, 256, 4, idx);                         // len 64 (chunk TN bound!)
  gmax_kernel<<<dim3(64, B), 64, 0, stream>>>(x2T, idx, n3f, 256, 64, 20, 255);
  // level 3
  edge1_b(n3f, 64, 8, 10, ec10a, ec10q, hA);             // len 8
  edge1_b(hA, 64, 8, 10, ec11a, ec11q, x3T);
  pool_kernel<<<dim3(4,1,4), 256, 0, stream>>>(x3T, w_pn12, dtf, partial, 64, 64, 21);
  reluadd_kernel<<<dim3(64), 256, 0, stream>>>(x3T, n3f, 4*64*64);
  // ---- idx, P, hA, n1f, n2f dead -> h3T/h2T/h1T aliases live ----
  gred_kernel<<<dim3(16), 256, 0, stream>>>(partial, g, 22);
  gw_kernel<<<dim3(256, 4), 64, 0, stream>>>(g, w_pn13, dtf, gW);
  mlp_kernel<<<dim3(16, B), 256, 0, stream>>>(gW, x3T, nullptr, 64, 64, wp13,
                                              nullptr, 0, nullptr, h3T, 64, 256);
  knn_f(3, 1, 256, 64, 1, idxU2);                        // len 64
  mlp_kernel<<<dim3(64, B), 256, 0, stream>>>(nullptr, h3T, idxU2, 64, 256, wt14,
                                              x2T, 64, wt14 + 256*256, h2T, 256, 256);
  knn_f(3, 1, 1024, 256, 4, idxU1);                      // len 64
  mlp_kernel<<<dim3(256, B), 256, 0, stream>>>(nullptr, h2T, idxU1, 256, 256, wt15,
                                               x1T, 64, wt15 + 256*256, h1T, 1024, 256);
  knn_f(3, 1, 4096, 1024, 4, idxU0);                     // len 256
  dec0_kernel<<<dim3(1024, B), 128, 0, stream>>>(h1T, idxU0, x0T, wt16, w_c17, dtf, out);
}

// Round 10
// 5386.451 us; speedup vs baseline: 2.0754x; 1.0715x over previous
//
#include <hip/hip_runtime.h>
#include <hip/hip_bf16.h>
#include <float.h>

typedef __hip_bfloat16 bf16;

#define NEG_BIG (-1.0e30f)

__device__ __forceinline__ bf16 f2b(float v){ return __float2bfloat16(v); }
__device__ __forceinline__ float lrelu(float x){ return x >= 0.f ? x : 0.2f*x; }

// dtype-flexible sanitized load from a raw INPUT buffer (element index)
__device__ __forceinline__ float ldx(const void* p, size_t i, int isbf){
  float v = isbf ? __bfloat162float(((const bf16*)p)[i]) : ((const float*)p)[i];
  return (v == v && fabsf(v) < 1e30f) ? v : 0.f;
}
// dtype-flexible store to the OUTPUT buffer (element index)
__device__ __forceinline__ void stout(void* p, size_t i, float v, int isbf){
  if (isbf) ((bf16*)p)[i] = f2b(v);
  else      ((float*)p)[i] = v;
}

// ---------------- input dtype detector ----------------
__global__ void detect_kernel(const unsigned int* __restrict__ X, int* __restrict__ flag){
  __shared__ int cnt;
  if (threadIdx.x == 0) cnt = 0;
  __syncthreads();
  int hits = 0;
  for (int i = threadIdx.x; i < 8192; i += 256){
    unsigned w = X[i];
    unsigned lo = w & 0xFFFFu;
    unsigned e = (lo >> 7) & 0xFFu;
    if ((e >= 0x76u && e <= 0x84u) || lo == 0u) hits++;
  }
  atomicAdd(&cnt, hits);
  __syncthreads();
  if (threadIdx.x == 0) flag[0] = (cnt > 4096) ? 1 : 0;
}

// ---------------- weight prep ----------------
__global__ void wt_kernel(const void* __restrict__ W, const int* __restrict__ dtf,
                          int Cout, int pitch, int coff, int Cin, float* __restrict__ WT){
  int i = blockIdx.x*256 + threadIdx.x;
  if (i >= Cin*Cout) return;
  int isbf = *dtf;
  int c = i / Cout, o = i - c*Cout;
  WT[i] = ldx(W, (size_t)o*pitch + coff + c, isbf);
}

__global__ void w0_kernel(const void* __restrict__ W0, const int* __restrict__ dtf,
                          int C, float* __restrict__ WaT, float* __restrict__ WqT){
  int i = blockIdx.x*256 + threadIdx.x;
  if (i >= C*64) return;
  int isbf = *dtf;
  int c = i >> 6, o = i & 63;
  float a = ldx(W0, (size_t)o*2*C + c, isbf);
  float q = ldx(W0, (size_t)o*2*C + C + c, isbf);
  WaT[i] = a; WqT[i] = q - a;
}

__global__ void xconv_kernel(const void* __restrict__ x, const int* __restrict__ dtf,
                             float* __restrict__ xfT){
  int i = blockIdx.x*256 + threadIdx.x;
  if (i >= 4*4096) return;
  int isbf = *dtf;
  int b = i >> 12, n = i & 4095;
  for (int c = 0; c < 9; c++)
    xfT[((size_t)b*4096 + n)*9 + c] = ldx(x, ((size_t)b*9 + c)*4096 + n, isbf);
}

__global__ void nodecopy_kernel(const void* __restrict__ x, const int* __restrict__ dtf,
                                void* __restrict__ out){
  int i = blockIdx.x*256 + threadIdx.x;
  int isbf = *dtf;
  if (i < 12288){
    int b = i / 3072, r = i % 3072; int c = r / 1024, m = r % 1024;
    stout(out, 212992 + i, ldx(x, ((size_t)b*9 + c)*4096 + m, isbf), isbf);
  } else if (i < 15360){
    int j = i - 12288; int b = j / 768, r = j % 768; int c = r / 256, m = r % 256;
    stout(out, 212992 + i, ldx(x, ((size_t)b*9 + c)*4096 + m, isbf), isbf);
  } else if (i < 16128){
    int j = i - 15360; int b = j / 192, r = j % 192; int c = r / 64, m = r % 64;
    stout(out, 212992 + i, ldx(x, ((size_t)b*9 + c)*4096 + m, isbf), isbf);
  }
}

// ---------------- kNN ----------------
__global__ void rownorm_kernel(const float* __restrict__ T, int pitch, size_t bs,
                               int C, int N, float* __restrict__ rr){
  int n = blockIdx.x*256 + threadIdx.x;
  int b = blockIdx.y;
  if (n >= N) return;
  const float* row = T + (size_t)b*bs + (size_t)n*pitch;
  float s = 0.f;
  for (int c = 0; c < C; c++) s = fmaf(row[c], row[c], s);
  rr[b*N + n] = s;
}

// small-C chunked kNN (C=3/9; per-thread query in registers, refs staged in LDS)
// REQUIREMENT: len = N/NC must be a multiple of TN.
template<int C, int K, int TN>
__global__ void knn_chunk_kernel(const float* __restrict__ qT, int qpitch, size_t qbs,
                                 const float* __restrict__ rT, int rpitch, size_t rbs,
                                 const float* __restrict__ rr, int M, int N, int NC,
                                 float* __restrict__ cval, int* __restrict__ cidx){
  __shared__ float sR[TN*C];
  __shared__ float sN[TN];
  int tid = threadIdx.x;
  int m = blockIdx.x*256 + tid;
  int cid = blockIdx.y, b = blockIdx.z;
  int len = N / NC;
  int n0 = cid * len;
  bool active = (m < M);
  float q[C]; float qq = 0.f;
  if (active){
    const float* qrow = qT + (size_t)b*qbs + (size_t)m*qpitch;
    #pragma unroll
    for (int c = 0; c < C; c++){ q[c] = qrow[c]; qq = fmaf(q[c], q[c], qq); }
  }
  float bv[K]; int bi[K];
  #pragma unroll
  for (int j = 0; j < K; j++){ bv[j] = NEG_BIG; bi[j] = n0; }
  float minv = NEG_BIG; int minpos = 0;
  auto ins = [&](float d, int j){
    if (d > minv){
      #pragma unroll
      for (int s = 0; s < K; s++) if (s == minpos){ bv[s] = d; bi[s] = j; }
      minv = bv[0]; minpos = 0;
      #pragma unroll
      for (int s = 1; s < K; s++) if (bv[s] < minv){ minv = bv[s]; minpos = s; }
    }
  };
  const float* rbase = rT + (size_t)b*rbs;
  const float* rrb = rr + b*N;
  for (int t0 = 0; t0 < len; t0 += TN){
    __syncthreads();
    for (int i = tid; i < TN*C; i += 256){
      int t = i / C, c = i - t*C;
      sR[i] = rbase[(size_t)(n0 + t0 + t)*rpitch + c];
    }
    for (int i = tid; i < TN; i += 256) sN[i] = rrb[n0 + t0 + i];
    __syncthreads();
    if (active){
      for (int t = 0; t < TN; t += 4){
        float a0 = 0.f, a1 = 0.f, a2 = 0.f, a3 = 0.f;
        #pragma unroll
        for (int c = 0; c < C; c++){
          float qc = q[c];
          a0 = fmaf(qc, sR[(t+0)*C + c], a0);
          a1 = fmaf(qc, sR[(t+1)*C + c], a1);
          a2 = fmaf(qc, sR[(t+2)*C + c], a2);
          a3 = fmaf(qc, sR[(t+3)*C + c], a3);
        }
        int jb = n0 + t0 + t;
        ins(2.f*a0 - qq - sN[t+0], jb+0);
        ins(2.f*a1 - qq - sN[t+1], jb+1);
        ins(2.f*a2 - qq - sN[t+2], jb+2);
        ins(2.f*a3 - qq - sN[t+3], jb+3);
      }
    }
  }
  if (active){
    float* ov = cval + ((size_t)((size_t)b*M + m)*NC + cid)*K;
    int*   oi = cidx + ((size_t)((size_t)b*M + m)*NC + cid)*K;
    #pragma unroll
    for (int j = 0; j < K; j++){ ov[j] = bv[j]; oi[j] = bi[j]; }
  }
}

// C=64 self-kNN scan: 1-wave blocks, 64 queries, query row held in VGPRs
// (q4[16] float4); refs read wave-uniform float4 (L1 broadcast); zero LDS.
// __launch_bounds__(64,2) permits up to 256 VGPR (need ~130) -> no spill,
// occupancy VGPR-capped at ~4 waves/SIMD. Merge stays a separate kernel.
template<int K>
__launch_bounds__(64, 2)
__global__ void knn64_kernel(const float* __restrict__ fT, const float* __restrict__ rr,
                             int N, int NC, float* __restrict__ cval, int* __restrict__ cidx){
  int lane = threadIdx.x;
  int q0 = blockIdx.x*64;
  int cid = blockIdx.y, b = blockIdx.z;
  int m = q0 + lane;
  int len = N / NC;
  int n0 = cid*len;
  float4 q4[16];
  {
    const float4* qp = (const float4*)(fT + ((size_t)b*N + m)*64);
    #pragma unroll
    for (int i = 0; i < 16; i++) q4[i] = qp[i];
  }
  float qq = rr[(size_t)b*N + m];   // self-kNN (M==N)
  float bv[K]; int bi[K];
  #pragma unroll
  for (int j = 0; j < K; j++){ bv[j] = NEG_BIG; bi[j] = n0; }
  float minv = NEG_BIG; int minpos = 0;
  auto ins = [&](float d, int j){
    if (d > minv){
      #pragma unroll
      for (int s = 0; s < K; s++) if (s == minpos){ bv[s] = d; bi[s] = j; }
      minv = bv[0]; minpos = 0;
      #pragma unroll
      for (int s = 1; s < K; s++) if (bv[s] < minv){ minv = bv[s]; minpos = s; }
    }
  };
  const float4* rbase = (const float4*)(fT + ((size_t)b*N + n0)*64);
  const float* rrb = rr + (size_t)b*N + n0;
  for (int t0 = 0; t0 < len; t0 += 4){
    const float4* r4 = rbase + (size_t)t0*16;
    float a0=0.f, a1=0.f, a2=0.f, a3=0.f;
    #pragma unroll
    for (int ct = 0; ct < 16; ct++){
      float4 v0 = r4[ct], v1 = r4[16+ct], v2 = r4[32+ct], v3 = r4[48+ct];
      float4 qv = q4[ct];
      a0 = fmaf(qv.x,v0.x,a0); a0 = fmaf(qv.y,v0.y,a0); a0 = fmaf(qv.z,v0.z,a0); a0 = fmaf(qv.w,v0.w,a0);
      a1 = fmaf(qv.x,v1.x,a1); a1 = fmaf(qv.y,v1.y,a1); a1 = fmaf(qv.z,v1.z,a1); a1 = fmaf(qv.w,v1.w,a1);
      a2 = fmaf(qv.x,v2.x,a2); a2 = fmaf(qv.y,v2.y,a2); a2 = fmaf(qv.z,v2.z,a2); a2 = fmaf(qv.w,v2.w,a2);
      a3 = fmaf(qv.x,v3.x,a3); a3 = fmaf(qv.y,v3.y,a3); a3 = fmaf(qv.z,v3.z,a3); a3 = fmaf(qv.w,v3.w,a3);
    }
    ins(2.f*a0 - qq - rrb[t0+0], n0+t0+0);
    ins(2.f*a1 - qq - rrb[t0+1], n0+t0+1);
    ins(2.f*a2 - qq - rrb[t0+2], n0+t0+2);
    ins(2.f*a3 - qq - rrb[t0+3], n0+t0+3);
  }
  float* ov = cval + ((size_t)((size_t)b*N + m)*NC + cid)*K;
  int*   oi = cidx + ((size_t)((size_t)b*N + m)*NC + cid)*K;
  #pragma unroll
  for (int j = 0; j < K; j++){ ov[j] = bv[j]; oi[j] = bi[j]; }
}

template<int K>
__global__ void knn_merge_kernel(const float* __restrict__ cval, const int* __restrict__ cidx,
                                 int M, int NC, int* __restrict__ idxo){
  int i = blockIdx.x*256 + threadIdx.x;   // b*M + m
  if (i >= 4*M) return;
  const float* cv = cval + (size_t)i*NC*K;
  const int*   ci = cidx + (size_t)i*NC*K;
  float bv[K]; int bi[K];
  #pragma unroll
  for (int j = 0; j < K; j++){ bv[j] = NEG_BIG; bi[j] = 0; }
  float minv = NEG_BIG; int minpos = 0;
  int T = NC*K;
  for (int t = 0; t < T; t++){
    float d = cv[t];
    if (d > minv){
      int j = ci[t];
      #pragma unroll
      for (int s = 0; s < K; s++) if (s == minpos){ bv[s] = d; bi[s] = j; }
      minv = bv[0]; minpos = 0;
      #pragma unroll
      for (int s = 1; s < K; s++) if (bv[s] < minv){ minv = bv[s]; minpos = s; }
    }
  }
  int* orow = idxo + (size_t)i*K;
  #pragma unroll
  for (int j = 0; j < K; j++) orow[j] = bi[j];
}

// ---------------- edge conv ----------------
__global__ void pq_kernel(const float* __restrict__ xT, int pitch, int C,
                          const float* __restrict__ WaT,
                          float* __restrict__ P, int N){
  int o = threadIdx.x & 63;
  int n = blockIdx.x*4 + (threadIdx.x >> 6);
  int b = blockIdx.y;
  if (n >= N) return;
  const float* row = xT + ((size_t)b*N + n)*pitch;
  float ap = 0.f;
  for (int c = 0; c < C; c++) ap = fmaf(WaT[c*64 + o], row[c], ap);
  P[((size_t)b*N + n)*64 + o] = ap;
}

// 4 points per 256-thread block: shared W1 tile (staged once), per-point sH.
// REQUIREMENT: N % 4 == 0.
__global__ void edge2_kernel(const float* __restrict__ P, const float* __restrict__ featT,
                             int pitch, int C, const float* __restrict__ WqT,
                             const int* __restrict__ idx, const float* __restrict__ W1T,
                             float* __restrict__ outT, int N, int mask){
  __shared__ float sW[64*64];     // [c][o]
  __shared__ float sH[4*20*64];   // [t][kk][c]
  __shared__ float sx[4*64];
  int tid = threadIdx.x;
  int o = tid & 63, t = tid >> 6;
  int n = blockIdx.x*4 + t;
  int b = blockIdx.y;
  const float4* w4 = (const float4*)W1T;
  float4* s4 = (float4*)sW;
  for (int i = tid; i < 1024; i += 256) s4[i] = w4[i];
  if (o < C) sx[t*64 + o] = featT[((size_t)b*N + n)*pitch + o];
  __syncthreads();
  float qv = 0.f;
  for (int c = 0; c < C; c++) qv = fmaf(WqT[c*64 + o], sx[t*64 + c], qv);
  const float* Pb = P + (size_t)b*N*64;
  const int* irow = idx + ((size_t)b*N + n)*20;
  float* sHt = sH + t*1280;
  for (int kk = 0; kk < 20; kk++){
    int j = irow[kk] & mask;
    float h = Pb[(size_t)j*64 + o] + qv;
    sHt[kk*64 + o] = h >= 0.f ? h : 0.2f*h;
  }
  __syncthreads();
  float acc[20];
  #pragma unroll
  for (int kk = 0; kk < 20; kk++) acc[kk] = 0.f;
  for (int c = 0; c < 64; c += 4){
    float w0 = sW[c*64+o], w1 = sW[(c+1)*64+o], w2 = sW[(c+2)*64+o], w3 = sW[(c+3)*64+o];
    #pragma unroll
    for (int kk = 0; kk < 20; kk++){
      float4 h4 = *(const float4*)&sHt[kk*64 + c];
      float a = acc[kk];
      a = fmaf(w0, h4.x, a); a = fmaf(w1, h4.y, a);
      a = fmaf(w2, h4.z, a); a = fmaf(w3, h4.w, a);
      acc[kk] = a;
    }
  }
  float m = NEG_BIG;
  #pragma unroll
  for (int kk = 0; kk < 20; kk++) m = fmaxf(m, acc[kk]);
  outT[((size_t)b*N + n)*64 + o] = lrelu(m);
}

// 4 points per 256-thread block. REQUIREMENT: N % 4 == 0.
__global__ void edge1_kernel(const float* __restrict__ P, const float* __restrict__ featT,
                             int pitch, int C, const float* __restrict__ WqT,
                             const int* __restrict__ idx, float* __restrict__ outT,
                             int N, int K, int mask){
  __shared__ float sx[4*64];
  int tid = threadIdx.x;
  int o = tid & 63, t = tid >> 6;
  int n = blockIdx.x*4 + t;
  int b = blockIdx.y;
  if (o < C) sx[t*64 + o] = featT[((size_t)b*N + n)*pitch + o];
  __syncthreads();
  float qv = 0.f;
  for (int c = 0; c < C; c++) qv = fmaf(WqT[c*64 + o], sx[t*64 + c], qv);
  const float* Pb = P + (size_t)b*N*64;
  const int* irow = idx + ((size_t)b*N + n)*K;
  float m = NEG_BIG;
  for (int kk = 0; kk < K; kk++){
    int j = irow[kk] & mask;
    m = fmaxf(m, Pb[(size_t)j*64 + o] + qv);
  }
  outT[((size_t)b*N + n)*64 + o] = lrelu(m);
}

__global__ void gmax_kernel(const float* __restrict__ inT, const int* __restrict__ idx,
                            float* __restrict__ outT, int Nin, int M, int K, int mask){
  int o = threadIdx.x; int m = blockIdx.x; int b = blockIdx.y;
  const float* ib = inT + (size_t)b*Nin*64;
  const int* irow = idx + ((size_t)b*M + m)*K;
  float v = NEG_BIG;
  for (int kk = 0; kk < K; kk++){
    int j = irow[kk] & mask;
    v = fmaxf(v, ib[(size_t)j*64 + o]);
  }
  outT[((size_t)b*M + m)*64 + o] = v;
}

__global__ void reluadd_kernel(float* __restrict__ x, const float* __restrict__ f, int total){
  int i = blockIdx.x*256 + threadIdx.x;
  if (i >= total) return;
  float v = x[i] + f[i];
  x[i] = v > 0.f ? v : 0.f;
}

// ---------------- global feature path ----------------
__global__ void pool_kernel(const float* __restrict__ xT, const void* __restrict__ W,
                            const int* __restrict__ dtf, float* __restrict__ partial,
                            int N, int npts, int segbase){
  __shared__ float sW[64*256];
  __shared__ float sX[32*64];
  int tid = threadIdx.x;
  int ot = blockIdx.x, chunk = blockIdx.y, b = blockIdx.z;
  int isbf = *dtf;
  for (int i = tid; i < 64*256; i += 256){
    int c = i >> 8, t = i & 255;
    sW[i] = ldx(W, (size_t)(ot*256 + t)*64 + c, isbf);
  }
  int n0 = chunk * npts;
  float m = NEG_BIG;
  for (int s0 = 0; s0 < npts; s0 += 32){
    __syncthreads();
    const float4* src = (const float4*)(xT + ((size_t)b*N + n0 + s0)*64);
    float4* dst = (float4*)sX;
    for (int i = tid; i < 512; i += 256) dst[i] = src[i];
    __syncthreads();
    for (int t = 0; t < 32; t += 4){
      float a0=0.f, a1=0.f, a2=0.f, a3=0.f;
      #pragma unroll
      for (int c = 0; c < 64; c++){
        float wv = sW[c*256 + tid];
        a0 = fmaf(wv, sX[(t+0)*64+c], a0);
        a1 = fmaf(wv, sX[(t+1)*64+c], a1);
        a2 = fmaf(wv, sX[(t+2)*64+c], a2);
        a3 = fmaf(wv, sX[(t+3)*64+c], a3);
      }
      m = fmaxf(m, fmaxf(fmaxf(a0,a1), fmaxf(a2,a3)));
    }
  }
  int o = ot*256 + tid;
  partial[((size_t)b*1024 + o)*22 + segbase + chunk] = m;
}

__global__ void gred_kernel(const float* __restrict__ partial, float* __restrict__ g, int S){
  int i = blockIdx.x*256 + threadIdx.x;
  if (i >= 4*1024) return;
  const float* p = partial + (size_t)i*22;
  float m = NEG_BIG;
  for (int s = 0; s < S; s++) m = fmaxf(m, p[s]);
  g[i] = lrelu(m);
}

__global__ void gw_kernel(const float* __restrict__ g, const void* __restrict__ W13,
                          const int* __restrict__ dtf, float* __restrict__ gW){
  int o = blockIdx.x, b = blockIdx.y;
  int lane = threadIdx.x;
  int isbf = *dtf;
  const float* gb = g + b*1024;
  float acc = 0.f;
  for (int c = lane; c < 1024; c += 64)
    acc = fmaf(ldx(W13, (size_t)o*1088 + c, isbf), gb[c], acc);
  for (int s = 32; s > 0; s >>= 1) acc += __shfl_down(acc, s, 64);
  if (lane == 0) gW[b*256 + o] = acc;
}

// ---------------- decoder MLPs (fused unpool gather) ----------------
__global__ void mlp_kernel(const float* __restrict__ base,
    const float* __restrict__ in1, const int* __restrict__ idx1, int N1, int C1,
    const float* __restrict__ W1T,
    const float* __restrict__ in2, int C2, const float* __restrict__ W2T,
    float* __restrict__ outT, int N, int Cout){
  __shared__ float sIn[4*320];
  int o = threadIdx.x, b = blockIdx.y;
  int n0 = blockIdx.x*4;
  int Cin = C1 + C2;
  int mask1 = N1 - 1;
  for (int t = 0; t < 4; t++){
    int n = n0 + t;
    int r1 = idx1 ? (idx1[(size_t)b*N + n] & mask1) : n;
    const float* p1 = in1 + ((size_t)b*N1 + r1)*C1;
    for (int c = o; c < C1; c += Cout) sIn[t*Cin + c] = p1[c];
    if (in2){
      const float* p2 = in2 + ((size_t)b*N + n)*C2;
      for (int c = o; c < C2; c += Cout) sIn[t*Cin + C1 + c] = p2[c];
    }
  }
  __syncthreads();
  float init = base ? base[b*Cout + o] : 0.f;
  float a0 = init, a1 = init, a2 = init, a3 = init;
  for (int c = 0; c < C1; c++){
    float wv = W1T[c*Cout + o];
    a0 = fmaf(wv, sIn[0*Cin + c], a0);
    a1 = fmaf(wv, sIn[1*Cin + c], a1);
    a2 = fmaf(wv, sIn[2*Cin + c], a2);
    a3 = fmaf(wv, sIn[3*Cin + c], a3);
  }
  for (int c = 0; c < C2; c++){
    float wv = W2T[c*Cout + o];
    a0 = fmaf(wv, sIn[0*Cin + C1 + c], a0);
    a1 = fmaf(wv, sIn[1*Cin + C1 + c], a1);
    a2 = fmaf(wv, sIn[2*Cin + C1 + c], a2);
    a3 = fmaf(wv, sIn[3*Cin + C1 + c], a3);
  }
  size_t ob = ((size_t)b*N + n0)*Cout + o;
  outT[ob]          = lrelu(a0);
  outT[ob + Cout]   = lrelu(a1);
  outT[ob + 2*Cout] = lrelu(a2);
  outT[ob + 3*Cout] = lrelu(a3);
}

__global__ void dec0_kernel(const float* __restrict__ h1T, const int* __restrict__ idxU0,
                            const float* __restrict__ x0T, const float* __restrict__ W16T,
                            const void* __restrict__ W17, const int* __restrict__ dtf,
                            void* __restrict__ out){
  __shared__ float sIn[4*320];
  __shared__ float sH0[4*128];
  int o = threadIdx.x;   // 128 threads
  int b = blockIdx.y; int n0 = blockIdx.x*4;
  for (int t = 0; t < 4; t++){
    int n = n0 + t;
    int r1 = idxU0[(size_t)b*4096 + n] & 1023;
    const float* p1 = h1T + ((size_t)b*1024 + r1)*256;
    for (int c = o; c < 256; c += 128) sIn[t*320 + c] = p1[c];
    const float* p2 = x0T + ((size_t)b*4096 + n)*64;
    if (o < 64) sIn[t*320 + 256 + o] = p2[o];
  }
  __syncthreads();
  float a0 = 0.f, a1 = 0.f, a2 = 0.f, a3 = 0.f;
  for (int c = 0; c < 256; c++){
    float wv = W16T[c*128 + o];
    a0 = fmaf(wv, sIn[0*320 + c], a0);
    a1 = fmaf(wv, sIn[1*320 + c], a1);
    a2 = fmaf(wv, sIn[2*320 + c], a2);
    a3 = fmaf(wv, sIn[3*320 + c], a3);
  }
  for (int c = 0; c < 64; c++){
    float wv = W16T[(256 + c)*128 + o];
    a0 = fmaf(wv, sIn[0*320 + 256 + c], a0);
    a1 = fmaf(wv, sIn[1*320 + 256 + c], a1);
    a2 = fmaf(wv, sIn[2*320 + 256 + c], a2);
    a3 = fmaf(wv, sIn[3*320 + 256 + c], a3);
  }
  sH0[0*128 + o] = lrelu(a0);
  sH0[1*128 + o] = lrelu(a1);
  sH0[2*128 + o] = lrelu(a2);
  sH0[3*128 + o] = lrelu(a3);
  __syncthreads();
  if (o < 52){
    int isbf = *dtf;
    int p = o / 13, cc = o % 13;
    float acc = 0.f;
    for (int c2 = 0; c2 < 128; c2++)
      acc = fmaf(ldx(W17, (size_t)cc*128 + c2, isbf), sH0[p*128 + c2], acc);
    if (!(acc == acc && fabsf(acc) < 1e30f)) acc = 0.f;
    stout(out, ((size_t)b*13 + cc)*4096 + (n0 + p), acc, isbf);
  }
}

// ---------------- host ----------------
extern "C" void kernel_launch(void* const* d_in, const int* in_sizes, int n_in,
                              void* d_out, int out_size, void* d_ws, size_t ws_size,
                              hipStream_t stream){
  (void)in_sizes; (void)n_in; (void)out_size;
  const int B = 4;
  const void* X       = d_in[0];
  const void* w_ec1_0 = d_in[1];
  const void* w_ec1_1 = d_in[2];
  const void* w_ec2_0 = d_in[3];
  const void* w_ec2_1 = d_in[4];
  const void* w_ec4_0 = d_in[5];
  const void* w_ec4_1 = d_in[6];
  const void* w_ec5_0 = d_in[7];
  const void* w_ec5_1 = d_in[8];
  const void* w_ec7   = d_in[9];
  const void* w_ec8   = d_in[10];
  const void* w_ec10  = d_in[11];
  const void* w_ec11  = d_in[12];
  const void* w_pn3   = d_in[13];
  const void* w_pn6   = d_in[14];
  const void* w_pn9   = d_in[15];
  const void* w_pn12  = d_in[16];
  const void* w_pn13  = d_in[17];
  const void* w_pn14  = d_in[18];
  const void* w_pn15  = d_in[19];
  const void* w_pn16  = d_in[20];
  const void* w_c17   = d_in[21];
  void* out = d_out;

  // ---- workspace layout (fp32 words; lifetime-aliased) ----
  float* wsf = (float*)d_ws;
  size_t off = 0;
  auto alloc = [&](size_t n)->float*{
    float* p = wsf + off; off += (n + 63) & ~(size_t)63; return p;
  };
  int*   dtf = (int*)alloc(64);
  float* xfT = alloc(4*4096*9);
  float* rr  = alloc(4*4096);
  float* partial = alloc(4*1024*22);
  float* g   = alloc(4*1024);
  float* gW  = alloc(4*256);
  int*   idx = (int*)alloc(4*4096*20);
  int*   idxU2 = (int*)alloc(4*256);
  int*   idxU1 = (int*)alloc(4*1024);
  int*   idxU0 = (int*)alloc(4*4096);
  float* ec1a = alloc(9*64);  float* ec1q = alloc(9*64);  float* ec1w1 = alloc(64*64);
  float* ec2a = alloc(64*64); float* ec2q = alloc(64*64); float* ec2w1 = alloc(64*64);
  float* ec4a = alloc(64*64); float* ec4q = alloc(64*64); float* ec4w1 = alloc(64*64);
  float* ec5a = alloc(64*64); float* ec5q = alloc(64*64); float* ec5w1 = alloc(64*64);
  float* ec7a = alloc(64*64); float* ec7q = alloc(64*64);
  float* ec8a = alloc(64*64); float* ec8q = alloc(64*64);
  float* ec10a = alloc(64*64); float* ec10q = alloc(64*64);
  float* ec11a = alloc(64*64); float* ec11q = alloc(64*64);
  float* wp13 = alloc(64*256);
  float* wt14 = alloc(320*256);
  float* wt15 = alloc(320*256);
  float* wt16 = alloc(320*128);
  float* P   = alloc(4*4096*64);
  float* hA  = alloc(4*4096*64);    // decoder: h1T alias (exact size)
  float* x0T = alloc(4*4096*64);
  float* x1T = alloc(4*1024*64);
  float* x2T = alloc(4*256*64);
  float* x3T = alloc(4*64*64);
  float* n1f = alloc(4*1024*64);    // decoder: h3T + head of h2T
  float* n2f = alloc(4*256*64);     // contiguous after n1f; h2T tail
  float* n3f = alloc(4*64*64);
  float* h1T = hA;
  float* h3T = n1f;
  float* h2T = n1f + 65536;

  // ws-aware candidate sizing (ws_size constant across calls)
  size_t rem = (ws_size/4 > off + 256) ? (ws_size/4 - off - 256) : 0;
  size_t half = rem / 2;
  int NCbig = (half >= (size_t)4*4096*16*20) ? 16 :
              (half >= (size_t)4*4096*8*20)  ? 8  : 4;
  size_t E = (size_t)4*4096*20*NCbig;
  float* cval = alloc(E);
  int*   cidx = (int*)alloc(E);

  detect_kernel<<<dim3(1), 256, 0, stream>>>((const unsigned int*)X, dtf);

  // ---- weight prep ----
  w0_kernel<<<dim3(3), 256, 0, stream>>>(w_ec1_0, dtf, 9, ec1a, ec1q);
  w0_kernel<<<dim3(16), 256, 0, stream>>>(w_ec2_0, dtf, 64, ec2a, ec2q);
  w0_kernel<<<dim3(16), 256, 0, stream>>>(w_ec4_0, dtf, 64, ec4a, ec4q);
  w0_kernel<<<dim3(16), 256, 0, stream>>>(w_ec5_0, dtf, 64, ec5a, ec5q);
  w0_kernel<<<dim3(16), 256, 0, stream>>>(w_ec7, dtf, 64, ec7a, ec7q);
  w0_kernel<<<dim3(16), 256, 0, stream>>>(w_ec8, dtf, 64, ec8a, ec8q);
  w0_kernel<<<dim3(16), 256, 0, stream>>>(w_ec10, dtf, 64, ec10a, ec10q);
  w0_kernel<<<dim3(16), 256, 0, stream>>>(w_ec11, dtf, 64, ec11a, ec11q);
  wt_kernel<<<dim3(16), 256, 0, stream>>>(w_ec1_1, dtf, 64, 64, 0, 64, ec1w1);
  wt_kernel<<<dim3(16), 256, 0, stream>>>(w_ec2_1, dtf, 64, 64, 0, 64, ec2w1);
  wt_kernel<<<dim3(16), 256, 0, stream>>>(w_ec4_1, dtf, 64, 64, 0, 64, ec4w1);
  wt_kernel<<<dim3(16), 256, 0, stream>>>(w_ec5_1, dtf, 64, 64, 0, 64, ec5w1);
  wt_kernel<<<dim3(64), 256, 0, stream>>>(w_pn13, dtf, 256, 1088, 1024, 64, wp13);
  wt_kernel<<<dim3(320), 256, 0, stream>>>(w_pn14, dtf, 256, 320, 0, 320, wt14);
  wt_kernel<<<dim3(320), 256, 0, stream>>>(w_pn15, dtf, 256, 320, 0, 320, wt15);
  wt_kernel<<<dim3(160), 256, 0, stream>>>(w_pn16, dtf, 128, 320, 0, 320, wt16);

  xconv_kernel<<<dim3(64), 256, 0, stream>>>(X, dtf, xfT);
  nodecopy_kernel<<<dim3(64), 256, 0, stream>>>(X, dtf, out);

  const size_t xbs = (size_t)4096*9;
  // coord-space kNN on xfT (pitch 9). len=N/NC must be multiple of 64.
  auto knn_f = [&](int C, int K, int M, int N, int NC, int* io){
    rownorm_kernel<<<dim3((N+255)/256, B), 256, 0, stream>>>(xfT, 9, xbs, C, N, rr);
    dim3 gd((M+255)/256, NC, B);
    if (C == 9)      knn_chunk_kernel<9,20,64><<<gd,256,0,stream>>>(xfT,9,xbs,xfT,9,xbs,rr,M,N,NC,cval,cidx);
    else if (K==20)  knn_chunk_kernel<3,20,64><<<gd,256,0,stream>>>(xfT,9,xbs,xfT,9,xbs,rr,M,N,NC,cval,cidx);
    else             knn_chunk_kernel<3,1,64><<<gd,256,0,stream>>>(xfT,9,xbs,xfT,9,xbs,rr,M,N,NC,cval,cidx);
    dim3 gm((4*M+255)/256);
    if (K == 20)     knn_merge_kernel<20><<<gm,256,0,stream>>>(cval,cidx,M,NC,io);
    else             knn_merge_kernel<1><<<gm,256,0,stream>>>(cval,cidx,M,NC,io);
  };
  // feature-space self-kNN (C=64), 1-wave blocks, queries in VGPRs
  auto knn_b = [&](int K, const float* fT, int N, int NC, int* io){
    rownorm_kernel<<<dim3((N+255)/256, B), 256, 0, stream>>>(fT, 64, (size_t)N*64, 64, N, rr);
    dim3 gd(N/64, NC, B);
    if (K == 20) knn64_kernel<20><<<gd,64,0,stream>>>(fT, rr, N, NC, cval, cidx);
    else         knn64_kernel<10><<<gd,64,0,stream>>>(fT, rr, N, NC, cval, cidx);
    dim3 gm((4*N+255)/256);
    if (K == 20) knn_merge_kernel<20><<<gm,256,0,stream>>>(cval,cidx,N,NC,io);
    else         knn_merge_kernel<10><<<gm,256,0,stream>>>(cval,cidx,N,NC,io);
  };
  auto edge2_b = [&](const float* fT, int N, int NC, float* wa, float* wq, float* w1, float* oT){
    knn_b(20, fT, N, NC, idx);
    pq_kernel<<<dim3((N+3)/4, B), 256, 0, stream>>>(fT, 64, 64, wa, P, N);
    edge2_kernel<<<dim3(N/4, B), 256, 0, stream>>>(P, fT, 64, 64, wq, idx, w1, oT, N, N-1);
  };
  auto edge1_b = [&](const float* fT, int N, int NC, int K, float* wa, float* wq, float* oT){
    knn_b(K, fT, N, NC, idx);
    pq_kernel<<<dim3((N+3)/4, B), 256, 0, stream>>>(fT, 64, 64, wa, P, N);
    edge1_kernel<<<dim3(N/4, B), 256, 0, stream>>>(P, fT, 64, 64, wq, idx, oT, N, K, N-1);
  };

  // level 0
  knn_f(9, 20, 4096, 4096, NCbig, idx);                  // len ≥ 256
  pq_kernel<<<dim3(1024, B), 256, 0, stream>>>(xfT, 9, 9, ec1a, P, 4096);
  edge2_kernel<<<dim3(1024, B), 256, 0, stream>>>(P, xfT, 9, 9, ec1q, idx, ec1w1, hA, 4096, 4095);
  edge2_b(hA, 4096, NCbig, ec2a, ec2q, ec2w1, x0T);
  pool_kernel<<<dim3(4,16,4), 256, 0, stream>>>(x0T, w_pn3, dtf, partial, 4096, 256, 0);
  // rand_pool 1
  knn_f(3, 20, 1024, 4096, 16, idx);                     // len 256
  gmax_kernel<<<dim3(1024, B), 64, 0, stream>>>(x0T, idx, n1f, 4096, 1024, 20, 4095);
  // level 1
  edge2_b(n1f, 1024, 16, ec4a, ec4q, ec4w1, hA);
  edge2_b(hA, 1024, 16, ec5a, ec5q, ec5w1, x1T);
  pool_kernel<<<dim3(4,4,4), 256, 0, stream>>>(x1T, w_pn6, dtf, partial, 1024, 256, 16);
  reluadd_kernel<<<dim3(1024), 256, 0, stream>>>(x1T, n1f, 4*1024*64);
  // rand_pool 2
  knn_f(3, 20, 256, 1024, 16, idx);                      // len 64
  gmax_kernel<<<dim3(256, B), 64, 0, stream>>>(x1T, idx, n2f, 1024, 256, 20, 1023);
  // level 2
  edge1_b(n2f, 256, 16, 20, ec7a, ec7q, hA);             // len 16
  edge1_b(hA, 256, 16, 20, ec8a, ec8q, x2T);
  pool_kernel<<<dim3(4,1,4), 256, 0, stream>>>(x2T, w_pn9, dtf, partial, 256, 256, 20);
  reluadd_kernel<<<dim3(256), 256, 0, stream>>>(x2T, n2f, 4*256*64);
  // rand_pool 3
  knn_f(3, 20, 64, 256, 4, idx);                         // len 64 (chunk TN bound)
  gmax_kernel<<<dim3(64, B), 64, 0, stream>>>(x2T, idx, n3f, 256, 64, 20, 255);
  // level 3
  edge1_b(n3f, 64, 8, 10, ec10a, ec10q, hA);             // len 8
  edge1_b(hA, 64, 8, 10, ec11a, ec11q, x3T);
  pool_kernel<<<dim3(4,1,4), 256, 0, stream>>>(x3T, w_pn12, dtf, partial, 64, 64, 21);
  reluadd_kernel<<<dim3(64), 256, 0, stream>>>(x3T, n3f, 4*64*64);
  // ---- idx, P, hA, n1f, n2f dead -> h3T/h2T/h1T aliases live ----
  gred_kernel<<<dim3(16), 256, 0, stream>>>(partial, g, 22);
  gw_kernel<<<dim3(256, 4), 64, 0, stream>>>(g, w_pn13, dtf, gW);
  mlp_kernel<<<dim3(16, B), 256, 0, stream>>>(gW, x3T, nullptr, 64, 64, wp13,
                                              nullptr, 0, nullptr, h3T, 64, 256);
  knn_f(3, 1, 256, 64, 1, idxU2);                        // len 64
  mlp_kernel<<<dim3(64, B), 256, 0, stream>>>(nullptr, h3T, idxU2, 64, 256, wt14,
                                              x2T, 64, wt14 + 256*256, h2T, 256, 256);
  knn_f(3, 1, 1024, 256, 4, idxU1);                      // len 64
  mlp_kernel<<<dim3(256, B), 256, 0, stream>>>(nullptr, h2T, idxU1, 256, 256, wt15,
                                               x1T, 64, wt15 + 256*256, h1T, 1024, 256);
  knn_f(3, 1, 4096, 1024, 4, idxU0);                     // len 256
  dec0_kernel<<<dim3(1024, B), 128, 0, stream>>>(h1T, idxU0, x0T, wt16, w_c17, dtf, out);
}

// Round 11
// 3562.766 us; speedup vs baseline: 3.1377x; 1.5119x over previous
//
#include <hip/hip_runtime.h>
#include <hip/hip_bf16.h>
#include <float.h>

typedef __hip_bfloat16 bf16;

#define NEG_BIG (-1.0e30f)

__device__ __forceinline__ bf16 f2b(float v){ return __float2bfloat16(v); }
__device__ __forceinline__ float lrelu(float x){ return x >= 0.f ? x : 0.2f*x; }

// dtype-flexible sanitized load from a raw INPUT buffer (element index)
__device__ __forceinline__ float ldx(const void* p, size_t i, int isbf){
  float v = isbf ? __bfloat162float(((const bf16*)p)[i]) : ((const float*)p)[i];
  return (v == v && fabsf(v) < 1e30f) ? v : 0.f;
}
// dtype-flexible store to the OUTPUT buffer (element index)
__device__ __forceinline__ void stout(void* p, size_t i, float v, int isbf){
  if (isbf) ((bf16*)p)[i] = f2b(v);
  else      ((float*)p)[i] = v;
}

// carry-chain sorted top-K insert (bv descending, bv[K-1] = min).
// Strict > : equal values keep the earlier (lower) index — matches lax.top_k.
// ~105 inst: 20 v_cmp + 80 cndmask, no dynamic indexing, no rescan.
template<int K>
__device__ __forceinline__ void topk_ins(float (&bv)[K], int (&bi)[K], float d, int j){
  if (d > bv[K-1]){
    bool gt[K];
    #pragma unroll
    for (int s = 0; s < K; s++) gt[s] = d > bv[s];
    #pragma unroll
    for (int s = K-1; s > 0; s--){
      float nv = gt[s-1] ? bv[s-1] : d;
      int   ni = gt[s-1] ? bi[s-1] : j;
      bv[s] = gt[s] ? nv : bv[s];
      bi[s] = gt[s] ? ni : bi[s];
    }
    if (gt[0]){ bv[0] = d; bi[0] = j; }
  }
}

// ---------------- input dtype detector ----------------
__global__ void detect_kernel(const unsigned int* __restrict__ X, int* __restrict__ flag){
  __shared__ int cnt;
  if (threadIdx.x == 0) cnt = 0;
  __syncthreads();
  int hits = 0;
  for (int i = threadIdx.x; i < 8192; i += 256){
    unsigned w = X[i];
    unsigned lo = w & 0xFFFFu;
    unsigned e = (lo >> 7) & 0xFFu;
    if ((e >= 0x76u && e <= 0x84u) || lo == 0u) hits++;
  }
  atomicAdd(&cnt, hits);
  __syncthreads();
  if (threadIdx.x == 0) flag[0] = (cnt > 4096) ? 1 : 0;
}

// ---------------- weight prep ----------------
__global__ void wt_kernel(const void* __restrict__ W, const int* __restrict__ dtf,
                          int Cout, int pitch, int coff, int Cin, float* __restrict__ WT){
  int i = blockIdx.x*256 + threadIdx.x;
  if (i >= Cin*Cout) return;
  int isbf = *dtf;
  int c = i / Cout, o = i - c*Cout;
  WT[i] = ldx(W, (size_t)o*pitch + coff + c, isbf);
}

__global__ void w0_kernel(const void* __restrict__ W0, const int* __restrict__ dtf,
                          int C, float* __restrict__ WaT, float* __restrict__ WqT){
  int i = blockIdx.x*256 + threadIdx.x;
  if (i >= C*64) return;
  int isbf = *dtf;
  int c = i >> 6, o = i & 63;
  float a = ldx(W0, (size_t)o*2*C + c, isbf);
  float q = ldx(W0, (size_t)o*2*C + C + c, isbf);
  WaT[i] = a; WqT[i] = q - a;
}

__global__ void xconv_kernel(const void* __restrict__ x, const int* __restrict__ dtf,
                             float* __restrict__ xfT){
  int i = blockIdx.x*256 + threadIdx.x;
  if (i >= 4*4096) return;
  int isbf = *dtf;
  int b = i >> 12, n = i & 4095;
  for (int c = 0; c < 9; c++)
    xfT[((size_t)b*4096 + n)*9 + c] = ldx(x, ((size_t)b*9 + c)*4096 + n, isbf);
}

__global__ void nodecopy_kernel(const void* __restrict__ x, const int* __restrict__ dtf,
                                void* __restrict__ out){
  int i = blockIdx.x*256 + threadIdx.x;
  int isbf = *dtf;
  if (i < 12288){
    int b = i / 3072, r = i % 3072; int c = r / 1024, m = r % 1024;
    stout(out, 212992 + i, ldx(x, ((size_t)b*9 + c)*4096 + m, isbf), isbf);
  } else if (i < 15360){
    int j = i - 12288; int b = j / 768, r = j % 768; int c = r / 256, m = r % 256;
    stout(out, 212992 + i, ldx(x, ((size_t)b*9 + c)*4096 + m, isbf), isbf);
  } else if (i < 16128){
    int j = i - 15360; int b = j / 192, r = j % 192; int c = r / 64, m = r % 64;
    stout(out, 212992 + i, ldx(x, ((size_t)b*9 + c)*4096 + m, isbf), isbf);
  }
}

// ---------------- kNN ----------------
__global__ void rownorm_kernel(const float* __restrict__ T, int pitch, size_t bs,
                               int C, int N, float* __restrict__ rr){
  int n = blockIdx.x*256 + threadIdx.x;
  int b = blockIdx.y;
  if (n >= N) return;
  const float* row = T + (size_t)b*bs + (size_t)n*pitch;
  float s = 0.f;
  for (int c = 0; c < C; c++) s = fmaf(row[c], row[c], s);
  rr[b*N + n] = s;
}

// small-C chunked kNN (C=3/9; per-thread query in registers, refs staged in LDS)
// REQUIREMENT: len = N/NC must be a multiple of TN.
template<int C, int K, int TN>
__global__ void knn_chunk_kernel(const float* __restrict__ qT, int qpitch, size_t qbs,
                                 const float* __restrict__ rT, int rpitch, size_t rbs,
                                 const float* __restrict__ rr, int M, int N, int NC,
                                 float* __restrict__ cval, int* __restrict__ cidx){
  __shared__ float sR[TN*C];
  __shared__ float sN[TN];
  int tid = threadIdx.x;
  int m = blockIdx.x*256 + tid;
  int cid = blockIdx.y, b = blockIdx.z;
  int len = N / NC;
  int n0 = cid * len;
  bool active = (m < M);
  float q[C]; float qq = 0.f;
  if (active){
    const float* qrow = qT + (size_t)b*qbs + (size_t)m*qpitch;
    #pragma unroll
    for (int c = 0; c < C; c++){ q[c] = qrow[c]; qq = fmaf(q[c], q[c], qq); }
  }
  float bv[K]; int bi[K];
  #pragma unroll
  for (int j = 0; j < K; j++){ bv[j] = NEG_BIG; bi[j] = n0; }
  const float* rbase = rT + (size_t)b*rbs;
  const float* rrb = rr + b*N;
  for (int t0 = 0; t0 < len; t0 += TN){
    __syncthreads();
    for (int i = tid; i < TN*C; i += 256){
      int t = i / C, c = i - t*C;
      sR[i] = rbase[(size_t)(n0 + t0 + t)*rpitch + c];
    }
    for (int i = tid; i < TN; i += 256) sN[i] = rrb[n0 + t0 + i];
    __syncthreads();
    if (active){
      for (int t = 0; t < TN; t += 4){
        float a0 = 0.f, a1 = 0.f, a2 = 0.f, a3 = 0.f;
        #pragma unroll
        for (int c = 0; c < C; c++){
          float qc = q[c];
          a0 = fmaf(qc, sR[(t+0)*C + c], a0);
          a1 = fmaf(qc, sR[(t+1)*C + c], a1);
          a2 = fmaf(qc, sR[(t+2)*C + c], a2);
          a3 = fmaf(qc, sR[(t+3)*C + c], a3);
        }
        int jb = n0 + t0 + t;
        topk_ins<K>(bv, bi, 2.f*a0 - qq - sN[t+0], jb+0);
        topk_ins<K>(bv, bi, 2.f*a1 - qq - sN[t+1], jb+1);
        topk_ins<K>(bv, bi, 2.f*a2 - qq - sN[t+2], jb+2);
        topk_ins<K>(bv, bi, 2.f*a3 - qq - sN[t+3], jb+3);
      }
    }
  }
  if (active){
    float* ov = cval + ((size_t)((size_t)b*M + m)*NC + cid)*K;
    int*   oi = cidx + ((size_t)((size_t)b*M + m)*NC + cid)*K;
    #pragma unroll
    for (int j = 0; j < K; j++){ ov[j] = bv[j]; oi[j] = bi[j]; }
  }
}

// C=64 self-kNN scan: 1-wave blocks, 64 queries, query row held in VGPRs;
// refs read wave-uniform float4 (L1 broadcast); zero LDS; no in-kernel merge.
template<int K>
__launch_bounds__(64, 2)
__global__ void knn64_kernel(const float* __restrict__ fT, const float* __restrict__ rr,
                             int N, int NC, float* __restrict__ cval, int* __restrict__ cidx){
  int lane = threadIdx.x;
  int q0 = blockIdx.x*64;
  int cid = blockIdx.y, b = blockIdx.z;
  int m = q0 + lane;
  int len = N / NC;
  int n0 = cid*len;
  float4 q4[16];
  {
    const float4* qp = (const float4*)(fT + ((size_t)b*N + m)*64);
    #pragma unroll
    for (int i = 0; i < 16; i++) q4[i] = qp[i];
  }
  float qq = rr[(size_t)b*N + m];   // self-kNN (M==N)
  float bv[K]; int bi[K];
  #pragma unroll
  for (int j = 0; j < K; j++){ bv[j] = NEG_BIG; bi[j] = n0; }
  const float4* rbase = (const float4*)(fT + ((size_t)b*N + n0)*64);
  const float* rrb = rr + (size_t)b*N + n0;
  for (int t0 = 0; t0 < len; t0 += 4){
    const float4* r4 = rbase + (size_t)t0*16;
    float a0=0.f, a1=0.f, a2=0.f, a3=0.f;
    #pragma unroll
    for (int ct = 0; ct < 16; ct++){
      float4 v0 = r4[ct], v1 = r4[16+ct], v2 = r4[32+ct], v3 = r4[48+ct];
      float4 qv = q4[ct];
      a0 = fmaf(qv.x,v0.x,a0); a0 = fmaf(qv.y,v0.y,a0); a0 = fmaf(qv.z,v0.z,a0); a0 = fmaf(qv.w,v0.w,a0);
      a1 = fmaf(qv.x,v1.x,a1); a1 = fmaf(qv.y,v1.y,a1); a1 = fmaf(qv.z,v1.z,a1); a1 = fmaf(qv.w,v1.w,a1);
      a2 = fmaf(qv.x,v2.x,a2); a2 = fmaf(qv.y,v2.y,a2); a2 = fmaf(qv.z,v2.z,a2); a2 = fmaf(qv.w,v2.w,a2);
      a3 = fmaf(qv.x,v3.x,a3); a3 = fmaf(qv.y,v3.y,a3); a3 = fmaf(qv.z,v3.z,a3); a3 = fmaf(qv.w,v3.w,a3);
    }
    topk_ins<K>(bv, bi, 2.f*a0 - qq - rrb[t0+0], n0+t0+0);
    topk_ins<K>(bv, bi, 2.f*a1 - qq - rrb[t0+1], n0+t0+1);
    topk_ins<K>(bv, bi, 2.f*a2 - qq - rrb[t0+2], n0+t0+2);
    topk_ins<K>(bv, bi, 2.f*a3 - qq - rrb[t0+3], n0+t0+3);
  }
  float* ov = cval + ((size_t)((size_t)b*N + m)*NC + cid)*K;
  int*   oi = cidx + ((size_t)((size_t)b*N + m)*NC + cid)*K;
  #pragma unroll
  for (int j = 0; j < K; j++){ ov[j] = bv[j]; oi[j] = bi[j]; }
}

template<int K>
__global__ void knn_merge_kernel(const float* __restrict__ cval, const int* __restrict__ cidx,
                                 int M, int NC, int* __restrict__ idxo){
  int i = blockIdx.x*256 + threadIdx.x;   // b*M + m
  if (i >= 4*M) return;
  const float* cv = cval + (size_t)i*NC*K;
  const int*   ci = cidx + (size_t)i*NC*K;
  float bv[K]; int bi[K];
  #pragma unroll
  for (int j = 0; j < K; j++){ bv[j] = NEG_BIG; bi[j] = 0; }
  int T = NC*K;
  for (int t = 0; t < T; t++)
    topk_ins<K>(bv, bi, cv[t], ci[t]);
  int* orow = idxo + (size_t)i*K;
  #pragma unroll
  for (int j = 0; j < K; j++) orow[j] = bi[j];
}

// ---------------- edge conv ----------------
__global__ void pq_kernel(const float* __restrict__ xT, int pitch, int C,
                          const float* __restrict__ WaT,
                          float* __restrict__ P, int N){
  int o = threadIdx.x & 63;
  int n = blockIdx.x*4 + (threadIdx.x >> 6);
  int b = blockIdx.y;
  if (n >= N) return;
  const float* row = xT + ((size_t)b*N + n)*pitch;
  float ap = 0.f;
  for (int c = 0; c < C; c++) ap = fmaf(WaT[c*64 + o], row[c], ap);
  P[((size_t)b*N + n)*64 + o] = ap;
}

// 4 points per 256-thread block: shared W1 tile, per-point sH. N % 4 == 0.
__global__ void edge2_kernel(const float* __restrict__ P, const float* __restrict__ featT,
                             int pitch, int C, const float* __restrict__ WqT,
                             const int* __restrict__ idx, const float* __restrict__ W1T,
                             float* __restrict__ outT, int N, int mask){
  __shared__ float sW[64*64];     // [c][o]
  __shared__ float sH[4*20*64];   // [t][kk][c]
  __shared__ float sx[4*64];
  int tid = threadIdx.x;
  int o = tid & 63, t = tid >> 6;
  int n = blockIdx.x*4 + t;
  int b = blockIdx.y;
  const float4* w4 = (const float4*)W1T;
  float4* s4 = (float4*)sW;
  for (int i = tid; i < 1024; i += 256) s4[i] = w4[i];
  if (o < C) sx[t*64 + o] = featT[((size_t)b*N + n)*pitch + o];
  __syncthreads();
  float qv = 0.f;
  for (int c = 0; c < C; c++) qv = fmaf(WqT[c*64 + o], sx[t*64 + c], qv);
  const float* Pb = P + (size_t)b*N*64;
  const int* irow = idx + ((size_t)b*N + n)*20;
  float* sHt = sH + t*1280;
  for (int kk = 0; kk < 20; kk++){
    int j = irow[kk] & mask;
    float h = Pb[(size_t)j*64 + o] + qv;
    sHt[kk*64 + o] = h >= 0.f ? h : 0.2f*h;
  }
  __syncthreads();
  float acc[20];
  #pragma unroll
  for (int kk = 0; kk < 20; kk++) acc[kk] = 0.f;
  for (int c = 0; c < 64; c += 4){
    float w0 = sW[c*64+o], w1 = sW[(c+1)*64+o], w2 = sW[(c+2)*64+o], w3 = sW[(c+3)*64+o];
    #pragma unroll
    for (int kk = 0; kk < 20; kk++){
      float4 h4 = *(const float4*)&sHt[kk*64 + c];
      float a = acc[kk];
      a = fmaf(w0, h4.x, a); a = fmaf(w1, h4.y, a);
      a = fmaf(w2, h4.z, a); a = fmaf(w3, h4.w, a);
      acc[kk] = a;
    }
  }
  float m = NEG_BIG;
  #pragma unroll
  for (int kk = 0; kk < 20; kk++) m = fmaxf(m, acc[kk]);
  outT[((size_t)b*N + n)*64 + o] = lrelu(m);
}

// 4 points per 256-thread block. N % 4 == 0.
__global__ void edge1_kernel(const float* __restrict__ P, const float* __restrict__ featT,
                             int pitch, int C, const float* __restrict__ WqT,
                             const int* __restrict__ idx, float* __restrict__ outT,
                             int N, int K, int mask){
  __shared__ float sx[4*64];
  int tid = threadIdx.x;
  int o = tid & 63, t = tid >> 6;
  int n = blockIdx.x*4 + t;
  int b = blockIdx.y;
  if (o < C) sx[t*64 + o] = featT[((size_t)b*N + n)*pitch + o];
  __syncthreads();
  float qv = 0.f;
  for (int c = 0; c < C; c++) qv = fmaf(WqT[c*64 + o], sx[t*64 + c], qv);
  const float* Pb = P + (size_t)b*N*64;
  const int* irow = idx + ((size_t)b*N + n)*K;
  float m = NEG_BIG;
  for (int kk = 0; kk < K; kk++){
    int j = irow[kk] & mask;
    m = fmaxf(m, Pb[(size_t)j*64 + o] + qv);
  }
  outT[((size_t)b*N + n)*64 + o] = lrelu(m);
}

__global__ void gmax_kernel(const float* __restrict__ inT, const int* __restrict__ idx,
                            float* __restrict__ outT, int Nin, int M, int K, int mask){
  int o = threadIdx.x; int m = blockIdx.x; int b = blockIdx.y;
  const float* ib = inT + (size_t)b*Nin*64;
  const int* irow = idx + ((size_t)b*M + m)*K;
  float v = NEG_BIG;
  for (int kk = 0; kk < K; kk++){
    int j = irow[kk] & mask;
    v = fmaxf(v, ib[(size_t)j*64 + o]);
  }
  outT[((size_t)b*M + m)*64 + o] = v;
}

__global__ void reluadd_kernel(float* __restrict__ x, const float* __restrict__ f, int total){
  int i = blockIdx.x*256 + threadIdx.x;
  if (i >= total) return;
  float v = x[i] + f[i];
  x[i] = v > 0.f ? v : 0.f;
}

// ---------------- global feature path ----------------
__global__ void pool_kernel(const float* __restrict__ xT, const void* __restrict__ W,
                            const int* __restrict__ dtf, float* __restrict__ partial,
                            int N, int npts, int segbase){
  __shared__ float sW[64*256];
  __shared__ float sX[32*64];
  int tid = threadIdx.x;
  int ot = blockIdx.x, chunk = blockIdx.y, b = blockIdx.z;
  int isbf = *dtf;
  for (int i = tid; i < 64*256; i += 256){
    int c = i >> 8, t = i & 255;
    sW[i] = ldx(W, (size_t)(ot*256 + t)*64 + c, isbf);
  }
  int n0 = chunk * npts;
  float m = NEG_BIG;
  for (int s0 = 0; s0 < npts; s0 += 32){
    __syncthreads();
    const float4* src = (const float4*)(xT + ((size_t)b*N + n0 + s0)*64);
    float4* dst = (float4*)sX;
    for (int i = tid; i < 512; i += 256) dst[i] = src[i];
    __syncthreads();
    for (int t = 0; t < 32; t += 4){
      float a0=0.f, a1=0.f, a2=0.f, a3=0.f;
      #pragma unroll
      for (int c = 0; c < 64; c++){
        float wv = sW[c*256 + tid];
        a0 = fmaf(wv, sX[(t+0)*64+c], a0);
        a1 = fmaf(wv, sX[(t+1)*64+c], a1);
        a2 = fmaf(wv, sX[(t+2)*64+c], a2);
        a3 = fmaf(wv, sX[(t+3)*64+c], a3);
      }
      m = fmaxf(m, fmaxf(fmaxf(a0,a1), fmaxf(a2,a3)));
    }
  }
  int o = ot*256 + tid;
  partial[((size_t)b*1024 + o)*22 + segbase + chunk] = m;
}

__global__ void gred_kernel(const float* __restrict__ partial, float* __restrict__ g, int S){
  int i = blockIdx.x*256 + threadIdx.x;
  if (i >= 4*1024) return;
  const float* p = partial + (size_t)i*22;
  float m = NEG_BIG;
  for (int s = 0; s < S; s++) m = fmaxf(m, p[s]);
  g[i] = lrelu(m);
}

__global__ void gw_kernel(const float* __restrict__ g, const void* __restrict__ W13,
                          const int* __restrict__ dtf, float* __restrict__ gW){
  int o = blockIdx.x, b = blockIdx.y;
  int lane = threadIdx.x;
  int isbf = *dtf;
  const float* gb = g + b*1024;
  float acc = 0.f;
  for (int c = lane; c < 1024; c += 64)
    acc = fmaf(ldx(W13, (size_t)o*1088 + c, isbf), gb[c], acc);
  for (int s = 32; s > 0; s >>= 1) acc += __shfl_down(acc, s, 64);
  if (lane == 0) gW[b*256 + o] = acc;
}

// ---------------- decoder MLPs (fused unpool gather) ----------------
__global__ void mlp_kernel(const float* __restrict__ base,
    const float* __restrict__ in1, const int* __restrict__ idx1, int N1, int C1,
    const float* __restrict__ W1T,
    const float* __restrict__ in2, int C2, const float* __restrict__ W2T,
    float* __restrict__ outT, int N, int Cout){
  __shared__ float sIn[4*320];
  int o = threadIdx.x, b = blockIdx.y;
  int n0 = blockIdx.x*4;
  int Cin = C1 + C2;
  int mask1 = N1 - 1;
  for (int t = 0; t < 4; t++){
    int n = n0 + t;
    int r1 = idx1 ? (idx1[(size_t)b*N + n] & mask1) : n;
    const float* p1 = in1 + ((size_t)b*N1 + r1)*C1;
    for (int c = o; c < C1; c += Cout) sIn[t*Cin + c] = p1[c];
    if (in2){
      const float* p2 = in2 + ((size_t)b*N + n)*C2;
      for (int c = o; c < C2; c += Cout) sIn[t*Cin + C1 + c] = p2[c];
    }
  }
  __syncthreads();
  float init = base ? base[b*Cout + o] : 0.f;
  float a0 = init, a1 = init, a2 = init, a3 = init;
  for (int c = 0; c < C1; c++){
    float wv = W1T[c*Cout + o];
    a0 = fmaf(wv, sIn[0*Cin + c], a0);
    a1 = fmaf(wv, sIn[1*Cin + c], a1);
    a2 = fmaf(wv, sIn[2*Cin + c], a2);
    a3 = fmaf(wv, sIn[3*Cin + c], a3);
  }
  for (int c = 0; c < C2; c++){
    float wv = W2T[c*Cout + o];
    a0 = fmaf(wv, sIn[0*Cin + C1 + c], a0);
    a1 = fmaf(wv, sIn[1*Cin + C1 + c], a1);
    a2 = fmaf(wv, sIn[2*Cin + C1 + c], a2);
    a3 = fmaf(wv, sIn[3*Cin + C1 + c], a3);
  }
  size_t ob = ((size_t)b*N + n0)*Cout + o;
  outT[ob]          = lrelu(a0);
  outT[ob + Cout]   = lrelu(a1);
  outT[ob + 2*Cout] = lrelu(a2);
  outT[ob + 3*Cout] = lrelu(a3);
}

__global__ void dec0_kernel(const float* __restrict__ h1T, const int* __restrict__ idxU0,
                            const float* __restrict__ x0T, const float* __restrict__ W16T,
                            const void* __restrict__ W17, const int* __restrict__ dtf,
                            void* __restrict__ out){
  __shared__ float sIn[4*320];
  __shared__ float sH0[4*128];
  int o = threadIdx.x;   // 128 threads
  int b = blockIdx.y; int n0 = blockIdx.x*4;
  for (int t = 0; t < 4; t++){
    int n = n0 + t;
    int r1 = idxU0[(size_t)b*4096 + n] & 1023;
    const float* p1 = h1T + ((size_t)b*1024 + r1)*256;
    for (int c = o; c < 256; c += 128) sIn[t*320 + c] = p1[c];
    const float* p2 = x0T + ((size_t)b*4096 + n)*64;
    if (o < 64) sIn[t*320 + 256 + o] = p2[o];
  }
  __syncthreads();
  float a0 = 0.f, a1 = 0.f, a2 = 0.f, a3 = 0.f;
  for (int c = 0; c < 256; c++){
    float wv = W16T[c*128 + o];
    a0 = fmaf(wv, sIn[0*320 + c], a0);
    a1 = fmaf(wv, sIn[1*320 + c], a1);
    a2 = fmaf(wv, sIn[2*320 + c], a2);
    a3 = fmaf(wv, sIn[3*320 + c], a3);
  }
  for (int c = 0; c < 64; c++){
    float wv = W16T[(256 + c)*128 + o];
    a0 = fmaf(wv, sIn[0*320 + 256 + c], a0);
    a1 = fmaf(wv, sIn[1*320 + 256 + c], a1);
    a2 = fmaf(wv, sIn[2*320 + 256 + c], a2);
    a3 = fmaf(wv, sIn[3*320 + 256 + c], a3);
  }
  sH0[0*128 + o] = lrelu(a0);
  sH0[1*128 + o] = lrelu(a1);
  sH0[2*128 + o] = lrelu(a2);
  sH0[3*128 + o] = lrelu(a3);
  __syncthreads();
  if (o < 52){
    int isbf = *dtf;
    int p = o / 13, cc = o % 13;
    float acc = 0.f;
    for (int c2 = 0; c2 < 128; c2++)
      acc = fmaf(ldx(W17, (size_t)cc*128 + c2, isbf), sH0[p*128 + c2], acc);
    if (!(acc == acc && fabsf(acc) < 1e30f)) acc = 0.f;
    stout(out, ((size_t)b*13 + cc)*4096 + (n0 + p), acc, isbf);
  }
}

// ---------------- host ----------------
extern "C" void kernel_launch(void* const* d_in, const int* in_sizes, int n_in,
                              void* d_out, int out_size, void* d_ws, size_t ws_size,
                              hipStream_t stream){
  (void)in_sizes; (void)n_in; (void)out_size;
  const int B = 4;
  const void* X       = d_in[0];
  const void* w_ec1_0 = d_in[1];
  const void* w_ec1_1 = d_in[2];
  const void* w_ec2_0 = d_in[3];
  const void* w_ec2_1 = d_in[4];
  const void* w_ec4_0 = d_in[5];
  const void* w_ec4_1 = d_in[6];
  const void* w_ec5_0 = d_in[7];
  const void* w_ec5_1 = d_in[8];
  const void* w_ec7   = d_in[9];
  const void* w_ec8   = d_in[10];
  const void* w_ec10  = d_in[11];
  const void* w_ec11  = d_in[12];
  const void* w_pn3   = d_in[13];
  const void* w_pn6   = d_in[14];
  const void* w_pn9   = d_in[15];
  const void* w_pn12  = d_in[16];
  const void* w_pn13  = d_in[17];
  const void* w_pn14  = d_in[18];
  const void* w_pn15  = d_in[19];
  const void* w_pn16  = d_in[20];
  const void* w_c17   = d_in[21];
  void* out = d_out;

  // ---- workspace layout (fp32 words; lifetime-aliased) ----
  float* wsf = (float*)d_ws;
  size_t off = 0;
  auto alloc = [&](size_t n)->float*{
    float* p = wsf + off; off += (n + 63) & ~(size_t)63; return p;
  };
  int*   dtf = (int*)alloc(64);
  float* xfT = alloc(4*4096*9);
  float* rr  = alloc(4*4096);
  float* partial = alloc(4*1024*22);
  float* g   = alloc(4*1024);
  float* gW  = alloc(4*256);
  int*   idx = (int*)alloc(4*4096*20);
  int*   idxU2 = (int*)alloc(4*256);
  int*   idxU1 = (int*)alloc(4*1024);
  int*   idxU0 = (int*)alloc(4*4096);
  float* ec1a = alloc(9*64);  float* ec1q = alloc(9*64);  float* ec1w1 = alloc(64*64);
  float* ec2a = alloc(64*64); float* ec2q = alloc(64*64); float* ec2w1 = alloc(64*64);
  float* ec4a = alloc(64*64); float* ec4q = alloc(64*64); float* ec4w1 = alloc(64*64);
  float* ec5a = alloc(64*64); float* ec5q = alloc(64*64); float* ec5w1 = alloc(64*64);
  float* ec7a = alloc(64*64); float* ec7q = alloc(64*64);
  float* ec8a = alloc(64*64); float* ec8q = alloc(64*64);
  float* ec10a = alloc(64*64); float* ec10q = alloc(64*64);
  float* ec11a = alloc(64*64); float* ec11q = alloc(64*64);
  float* wp13 = alloc(64*256);
  float* wt14 = alloc(320*256);
  float* wt15 = alloc(320*256);
  float* wt16 = alloc(320*128);
  float* P   = alloc(4*4096*64);
  float* hA  = alloc(4*4096*64);    // decoder: h1T alias (exact size)
  float* x0T = alloc(4*4096*64);
  float* x1T = alloc(4*1024*64);
  float* x2T = alloc(4*256*64);
  float* x3T = alloc(4*64*64);
  float* n1f = alloc(4*1024*64);    // decoder: h3T + head of h2T
  float* n2f = alloc(4*256*64);     // contiguous after n1f; h2T tail
  float* n3f = alloc(4*64*64);
  float* h1T = hA;
  float* h3T = n1f;
  float* h2T = n1f + 65536;

  // ws-aware candidate sizing (ws_size constant across calls)
  size_t rem = (ws_size/4 > off + 256) ? (ws_size/4 - off - 256) : 0;
  size_t half = rem / 2;
  int NCbig = (half >= (size_t)4*4096*16*20) ? 16 :
              (half >= (size_t)4*4096*8*20)  ? 8  : 4;
  size_t E = (size_t)4*4096*20*NCbig;
  float* cval = alloc(E);
  int*   cidx = (int*)alloc(E);

  detect_kernel<<<dim3(1), 256, 0, stream>>>((const unsigned int*)X, dtf);

  // ---- weight prep ----
  w0_kernel<<<dim3(3), 256, 0, stream>>>(w_ec1_0, dtf, 9, ec1a, ec1q);
  w0_kernel<<<dim3(16), 256, 0, stream>>>(w_ec2_0, dtf, 64, ec2a, ec2q);
  w0_kernel<<<dim3(16), 256, 0, stream>>>(w_ec4_0, dtf, 64, ec4a, ec4q);
  w0_kernel<<<dim3(16), 256, 0, stream>>>(w_ec5_0, dtf, 64, ec5a, ec5q);
  w0_kernel<<<dim3(16), 256, 0, stream>>>(w_ec7, dtf, 64, ec7a, ec7q);
  w0_kernel<<<dim3(16), 256, 0, stream>>>(w_ec8, dtf, 64, ec8a, ec8q);
  w0_kernel<<<dim3(16), 256, 0, stream>>>(w_ec10, dtf, 64, ec10a, ec10q);
  w0_kernel<<<dim3(16), 256, 0, stream>>>(w_ec11, dtf, 64, ec11a, ec11q);
  wt_kernel<<<dim3(16), 256, 0, stream>>>(w_ec1_1, dtf, 64, 64, 0, 64, ec1w1);
  wt_kernel<<<dim3(16), 256, 0, stream>>>(w_ec2_1, dtf, 64, 64, 0, 64, ec2w1);
  wt_kernel<<<dim3(16), 256, 0, stream>>>(w_ec4_1, dtf, 64, 64, 0, 64, ec4w1);
  wt_kernel<<<dim3(16), 256, 0, stream>>>(w_ec5_1, dtf, 64, 64, 0, 64, ec5w1);
  wt_kernel<<<dim3(64), 256, 0, stream>>>(w_pn13, dtf, 256, 1088, 1024, 64, wp13);
  wt_kernel<<<dim3(320), 256, 0, stream>>>(w_pn14, dtf, 256, 320, 0, 320, wt14);
  wt_kernel<<<dim3(320), 256, 0, stream>>>(w_pn15, dtf, 256, 320, 0, 320, wt15);
  wt_kernel<<<dim3(160), 256, 0, stream>>>(w_pn16, dtf, 128, 320, 0, 320, wt16);

  xconv_kernel<<<dim3(64), 256, 0, stream>>>(X, dtf, xfT);
  nodecopy_kernel<<<dim3(64), 256, 0, stream>>>(X, dtf, out);

  const size_t xbs = (size_t)4096*9;
  // coord-space kNN on xfT (pitch 9). len=N/NC must be multiple of 64.
  auto knn_f = [&](int C, int K, int M, int N, int NC, int* io){
    rownorm_kernel<<<dim3((N+255)/256, B), 256, 0, stream>>>(xfT, 9, xbs, C, N, rr);
    dim3 gd((M+255)/256, NC, B);
    if (C == 9)      knn_chunk_kernel<9,20,64><<<gd,256,0,stream>>>(xfT,9,xbs,xfT,9,xbs,rr,M,N,NC,cval,cidx);
    else if (K==20)  knn_chunk_kernel<3,20,64><<<gd,256,0,stream>>>(xfT,9,xbs,xfT,9,xbs,rr,M,N,NC,cval,cidx);
    else             knn_chunk_kernel<3,1,64><<<gd,256,0,stream>>>(xfT,9,xbs,xfT,9,xbs,rr,M,N,NC,cval,cidx);
    dim3 gm((4*M+255)/256);
    if (K == 20)     knn_merge_kernel<20><<<gm,256,0,stream>>>(cval,cidx,M,NC,io);
    else             knn_merge_kernel<1><<<gm,256,0,stream>>>(cval,cidx,M,NC,io);
  };
  // feature-space self-kNN (C=64), 1-wave blocks, queries in VGPRs
  auto knn_b = [&](int K, const float* fT, int N, int NC, int* io){
    rownorm_kernel<<<dim3((N+255)/256, B), 256, 0, stream>>>(fT, 64, (size_t)N*64, 64, N, rr);
    dim3 gd(N/64, NC, B);
    if (K == 20) knn64_kernel<20><<<gd,64,0,stream>>>(fT, rr, N, NC, cval, cidx);
    else         knn64_kernel<10><<<gd,64,0,stream>>>(fT, rr, N, NC, cval, cidx);
    dim3 gm((4*N+255)/256);
    if (K == 20) knn_merge_kernel<20><<<gm,256,0,stream>>>(cval,cidx,N,NC,io);
    else         knn_merge_kernel<10><<<gm,256,0,stream>>>(cval,cidx,N,NC,io);
  };
  auto edge2_b = [&](const float* fT, int N, int NC, float* wa, float* wq, float* w1, float* oT){
    knn_b(20, fT, N, NC, idx);
    pq_kernel<<<dim3((N+3)/4, B), 256, 0, stream>>>(fT, 64, 64, wa, P, N);
    edge2_kernel<<<dim3(N/4, B), 256, 0, stream>>>(P, fT, 64, 64, wq, idx, w1, oT, N, N-1);
  };
  auto edge1_b = [&](const float* fT, int N, int NC, int K, float* wa, float* wq, float* oT){
    knn_b(K, fT, N, NC, idx);
    pq_kernel<<<dim3((N+3)/4, B), 256, 0, stream>>>(fT, 64, 64, wa, P, N);
    edge1_kernel<<<dim3(N/4, B), 256, 0, stream>>>(P, fT, 64, 64, wq, idx, oT, N, K, N-1);
  };

  // level 0
  knn_f(9, 20, 4096, 4096, NCbig, idx);                  // len ≥ 256
  pq_kernel<<<dim3(1024, B), 256, 0, stream>>>(xfT, 9, 9, ec1a, P, 4096);
  edge2_kernel<<<dim3(1024, B), 256, 0, stream>>>(P, xfT, 9, 9, ec1q, idx, ec1w1, hA, 4096, 4095);
  edge2_b(hA, 4096, NCbig, ec2a, ec2q, ec2w1, x0T);
  pool_kernel<<<dim3(4,16,4), 256, 0, stream>>>(x0T, w_pn3, dtf, partial, 4096, 256, 0);
  // rand_pool 1
  knn_f(3, 20, 1024, 4096, 16, idx);                     // len 256
  gmax_kernel<<<dim3(1024, B), 64, 0, stream>>>(x0T, idx, n1f, 4096, 1024, 20, 4095);
  // level 1
  edge2_b(n1f, 1024, 16, ec4a, ec4q, ec4w1, hA);
  edge2_b(hA, 1024, 16, ec5a, ec5q, ec5w1, x1T);
  pool_kernel<<<dim3(4,4,4), 256, 0, stream>>>(x1T, w_pn6, dtf, partial, 1024, 256, 16);
  reluadd_kernel<<<dim3(1024), 256, 0, stream>>>(x1T, n1f, 4*1024*64);
  // rand_pool 2
  knn_f(3, 20, 256, 1024, 16, idx);                      // len 64
  gmax_kernel<<<dim3(256, B), 64, 0, stream>>>(x1T, idx, n2f, 1024, 256, 20, 1023);
  // level 2
  edge1_b(n2f, 256, 16, 20, ec7a, ec7q, hA);             // len 16
  edge1_b(hA, 256, 16, 20, ec8a, ec8q, x2T);
  pool_kernel<<<dim3(4,1,4), 256, 0, stream>>>(x2T, w_pn9, dtf, partial, 256, 256, 20);
  reluadd_kernel<<<dim3(256), 256, 0, stream>>>(x2T, n2f, 4*256*64);
  // rand_pool 3
  knn_f(3, 20, 64, 256, 4, idx);                         // len 64 (chunk TN bound)
  gmax_kernel<<<dim3(64, B), 64, 0, stream>>>(x2T, idx, n3f, 256, 64, 20, 255);
  // level 3
  edge1_b(n3f, 64, 8, 10, ec10a, ec10q, hA);             // len 8
  edge1_b(hA, 64, 8, 10, ec11a, ec11q, x3T);
  pool_kernel<<<dim3(4,1,4), 256, 0, stream>>>(x3T, w_pn12, dtf, partial, 64, 64, 21);
  reluadd_kernel<<<dim3(64), 256, 0, stream>>>(x3T, n3f, 4*64*64);
  // ---- idx, P, hA, n1f, n2f dead -> h3T/h2T/h1T aliases live ----
  gred_kernel<<<dim3(16), 256, 0, stream>>>(partial, g, 22);
  gw_kernel<<<dim3(256, 4), 64, 0, stream>>>(g, w_pn13, dtf, gW);
  mlp_kernel<<<dim3(16, B), 256, 0, stream>>>(gW, x3T, nullptr, 64, 64, wp13,
                                              nullptr, 0, nullptr, h3T, 64, 256);
  knn_f(3, 1, 256, 64, 1, idxU2);                        // len 64
  mlp_kernel<<<dim3(64, B), 256, 0, stream>>>(nullptr, h3T, idxU2, 64, 256, wt14,
                                              x2T, 64, wt14 + 256*256, h2T, 256, 256);
  knn_f(3, 1, 1024, 256, 4, idxU1);                      // len 64
  mlp_kernel<<<dim3(256, B), 256, 0, stream>>>(nullptr, h2T, idxU1, 256, 256, wt15,
                                               x1T, 64, wt15 + 256*256, h1T, 1024, 256);
  knn_f(3, 1, 4096, 1024, 4, idxU0);                     // len 256
  dec0_kernel<<<dim3(1024, B), 128, 0, stream>>>(h1T, idxU0, x0T, wt16, w_c17, dtf, out);
}